// Round 7
// baseline (256.496 us; speedup 1.0000x reference)
//
#include <hip/hip_runtime.h>
#include <hip/hip_bf16.h>

#define D_MODEL 256
#define HEADS 4
#define HD 64
#define BATCH 4
#define SEQ 4096
#define NPOS (BATCH*SEQ)          // 16384 positions
#define SCALE_LOG2 0.18033688011112042f  // log2(e)/8, folded into q projection
#define MCHUNKS 2                 // flash m-split (partials add; no online max)

typedef __attribute__((ext_vector_type(4))) float floatx4;
typedef __attribute__((ext_vector_type(8))) short bf16x8;
typedef __attribute__((ext_vector_type(4))) short bf16x4;
typedef __attribute__((ext_vector_type(4))) unsigned short ushortx4;

__device__ __forceinline__ float bf2f(unsigned short b) {
    return __uint_as_float(((unsigned int)b) << 16);
}
__device__ __forceinline__ unsigned short f2bf(float f) {
    unsigned int u = __float_as_uint(f);
    return (unsigned short)((u + 0x7fffu + ((u >> 16) & 1u)) >> 16);
}
__device__ __forceinline__ bf16x4 pack_bf16x4(float a, float b, float c, float d) {
    __hip_bfloat162 lo = __float22bfloat162_rn(float2{a, b});
    __hip_bfloat162 hi = __float22bfloat162_rn(float2{c, d});
    union { __hip_bfloat162 h2[2]; bf16x4 v; } u;
    u.h2[0] = lo; u.h2[1] = hi;
    return u.v;
}
__device__ __forceinline__ bf16x8 pack_bf16x8(floatx4 a, floatx4 b) {
    union { bf16x4 h[2]; bf16x8 v; } u;
    u.h[0] = pack_bf16x4(a[0], a[1], a[2], a[3]);
    u.h[1] = pack_bf16x4(b[0], b[1], b[2], b[3]);
    return u.v;
}
#define MFMA(a,b,c) __builtin_amdgcn_mfma_f32_16x16x32_bf16((a),(b),(c),0,0,0)
#define EXP2(x) __builtin_amdgcn_exp2f(x)   // native v_exp_f32 (exp2f -> ocml is ~5x slower)

// ---------------------------------------------------------------------------
// prep: blocks [0,576): linear f32->bf16 weight copies (pq,pk,pv,mlp1,mlp2).
//       blocks [576,640): Wmt[c'][o] = merge_w[o][(c'&63)*4 + (c'>>6)].
//       blocks [640,1152): transpose x/source -> xT/srcT [pos][256] bf16.
// ---------------------------------------------------------------------------
__global__ __launch_bounds__(256) void prep(
        const float* __restrict__ pq_w, const float* __restrict__ pk_w,
        const float* __restrict__ pv_w, const float* __restrict__ merge_w,
        const float* __restrict__ mlp1_w, const float* __restrict__ mlp2_w,
        const float* __restrict__ x, const float* __restrict__ src,
        unsigned short* __restrict__ wqb, unsigned short* __restrict__ wkb,
        unsigned short* __restrict__ wvb, unsigned short* __restrict__ wmt,
        unsigned short* __restrict__ w1b, unsigned short* __restrict__ w2b,
        unsigned short* __restrict__ xT, unsigned short* __restrict__ srcT)
{
    __shared__ unsigned short lT[64][264];
    const int t = threadIdx.x;
    const int bx = blockIdx.x;
    if (bx < 576) {
        int linear = bx * 1024 + t * 4;
        const float* srcW; unsigned short* dst; int off;
        if (linear < 65536)       { srcW = pq_w;   dst = wqb; off = 0; }
        else if (linear < 131072) { srcW = pk_w;   dst = wkb; off = 65536; }
        else if (linear < 196608) { srcW = pv_w;   dst = wvb; off = 131072; }
        else if (linear < 458752) { srcW = mlp1_w; dst = w1b; off = 196608; }
        else                      { srcW = mlp2_w; dst = w2b; off = 458752; }
        int i = linear - off;
        float4 w = *(const float4*)&srcW[i];
        ushortx4 s = { f2bf(w.x), f2bf(w.y), f2bf(w.z), f2bf(w.w) };
        *(ushortx4*)&dst[i] = s;
        return;
    }
    if (bx < 640) {
        int i = (bx - 576) * 1024 + t * 4;
        int cp = i >> 8, o = i & 255;
        int pc = ((cp & 63) << 2) | (cp >> 6);
        unsigned short s[4];
#pragma unroll
        for (int j = 0; j < 4; ++j)
            s[j] = f2bf(merge_w[(size_t)(o + j) * 256 + pc]);
        *(ushortx4*)&wmt[i] = *(const ushortx4*)s;
        return;
    }
    int z = bx - 640;
    const float* X = (z < 256) ? x : src;
    unsigned short* O = (z < 256) ? xT : srcT;
    int rem = z & 255;
    int b = rem >> 6, n0 = (rem & 63) * 64;
#pragma unroll
    for (int r = 0; r < 16; ++r) {
        int idx = r * 256 + t;
        int ch = idx >> 4, nnq = (idx & 15) * 4;
        float4 v4 = *(const float4*)&X[((size_t)b * 256 + ch) * SEQ + n0 + nnq];
        lT[nnq + 0][ch] = f2bf(v4.x);
        lT[nnq + 1][ch] = f2bf(v4.y);
        lT[nnq + 2][ch] = f2bf(v4.z);
        lT[nnq + 3][ch] = f2bf(v4.w);
    }
    __syncthreads();
#pragma unroll
    for (int r = 0; r < 8; ++r) {
        int idx = r * 256 + t;
        int row = idx >> 5, cg = (idx & 31) * 8;
        *(bf16x8*)&O[((size_t)b * SEQ + n0 + row) * 256 + cg] = *(const bf16x8*)&lT[row][cg];
    }
}

// ---------------------------------------------------------------------------
// prep2: fold merge into mlp1.  y<8: w1f[o2][c'] = sum_o W1b[o2][o]*Wmt[c'][o];
// y==8: b1f[o2] = mlp1_b[o2] + sum_o W1b[o2][o]*merge_b[o].  grid (2,9).
// ---------------------------------------------------------------------------
__global__ __launch_bounds__(256) void prep2(
        const float* __restrict__ mlp1_w, const float* __restrict__ mlp1_b,
        const float* __restrict__ merge_b, const unsigned short* __restrict__ wmt,
        unsigned short* __restrict__ w1f, float* __restrict__ b1f)
{
    __shared__ unsigned short lA[64][40];
    __shared__ unsigned short lB[128][40];
    const int t = threadIdx.x;
    if (blockIdx.y == 8) {
        int o2 = blockIdx.x * 256 + t;
        float s = mlp1_b[o2];
        for (int o = 0; o < 256; ++o)
            s += mlp1_w[(size_t)o2 * 512 + 256 + o] * merge_b[o];
        b1f[o2] = s;
        return;
    }
    const int lane = t & 63, wid = t >> 6;
    const int wm = wid >> 1, wn = wid & 1;
    const int lrow = lane & 15, quad = lane >> 4;
    const int o20 = blockIdx.y * 64;
    const int c0  = blockIdx.x * 128;

    floatx4 acc[2][4];
#pragma unroll
    for (int i = 0; i < 2; ++i)
#pragma unroll
        for (int j = 0; j < 4; ++j) acc[i][j] = (floatx4){0.f,0.f,0.f,0.f};

    for (int k0 = 0; k0 < 256; k0 += 32) {
#pragma unroll
        for (int r = 0; r < 2; ++r) {
            int linear = r * 1024 + t * 4;
            int row = linear >> 5, col = linear & 31;
            float4 w = *(const float4*)&mlp1_w[(size_t)(o20 + row) * 512 + 256 + k0 + col];
            ushortx4 s = { f2bf(w.x), f2bf(w.y), f2bf(w.z), f2bf(w.w) };
            *(ushortx4*)&lA[row][col] = s;
        }
#pragma unroll
        for (int r = 0; r < 2; ++r) {
            int linear = r * 256 + t;
            int row = linear >> 2, cg = (linear & 3) * 8;
            *(bf16x8*)&lB[row][cg] = *(const bf16x8*)&wmt[(size_t)(c0 + row) * 256 + k0 + cg];
        }
        __syncthreads();
        bf16x8 aF[2], bF[4];
        const int kq = quad * 8;
#pragma unroll
        for (int mt = 0; mt < 2; ++mt)
            aF[mt] = *(const bf16x8*)&lA[wm*32 + mt*16 + lrow][kq];
#pragma unroll
        for (int nt = 0; nt < 4; ++nt)
            bF[nt] = *(const bf16x8*)&lB[wn*64 + nt*16 + lrow][kq];
#pragma unroll
        for (int mt = 0; mt < 2; ++mt)
#pragma unroll
            for (int nt = 0; nt < 4; ++nt)
                acc[mt][nt] = MFMA(aF[mt], bF[nt], acc[mt][nt]);
        __syncthreads();
    }
#pragma unroll
    for (int nt = 0; nt < 4; ++nt) {
        int cp = c0 + wn*64 + nt*16 + lrow;
#pragma unroll
        for (int mt = 0; mt < 2; ++mt)
#pragma unroll
            for (int j = 0; j < 4; ++j) {
                int o2 = o20 + wm*32 + mt*16 + quad*4 + j;
                w1f[(size_t)o2 * 256 + cp] = f2bf(acc[mt][nt][j]);
            }
    }
}

// ---------------------------------------------------------------------------
// Merged QKV projection, double-buffered LDS (R15: 1 barrier/k-step, was 2).
// grid (6, SEQ/128, B): mode = x>>1 (0=q,1=k,2=v), ob = (x&1)*128.
// R13 (kept): v-mode epilogue staged through LDS for coalesced bf16x8 stores.
// ---------------------------------------------------------------------------
__global__ __launch_bounds__(256) void proj_qkv_all(
        const unsigned short* __restrict__ Wq, const float* __restrict__ bq,
        const unsigned short* __restrict__ Wk, const float* __restrict__ bk,
        const unsigned short* __restrict__ Wv, const float* __restrict__ bv,
        const unsigned short* __restrict__ xT, const unsigned short* __restrict__ srcT,
        unsigned short* __restrict__ qo, unsigned short* __restrict__ ko,
        unsigned short* __restrict__ vo)
{
    __shared__ unsigned short smem[2][128 * 80];   // per buf: lA 128x40, lB 128x40
    unsigned short (*stage)[72] = (unsigned short (*)[72])&smem[0][0];
    unsigned short* stage2 = &smem[0][0];          // v-mode: flat [64][132] u16
    const int t = threadIdx.x;
    const int lane = t & 63, wid = t >> 6;
    const int wm = wid >> 1, wn = wid & 1;
    const int lrow = lane & 15, quad = lane >> 4;
    const int mode = blockIdx.x >> 1;
    const int ob = (blockIdx.x & 1) * 128;
    const int n0 = blockIdx.y * 128;
    const int b  = blockIdx.z;
    const unsigned short* W  = (mode == 0) ? Wq : (mode == 1) ? Wk : Wv;
    const float* bias        = (mode == 0) ? bq : (mode == 1) ? bk : bv;
    const unsigned short* XT = (mode == 0) ? xT : srcT;
    unsigned short* out      = (mode == 0) ? qo : (mode == 1) ? ko : vo;

    const int srow[2] = { (0*256 + t) >> 2, (1*256 + t) >> 2 };
    const int scg = (t & 3) * 8;

    floatx4 acc[4][4];
#pragma unroll
    for (int i = 0; i < 4; ++i)
#pragma unroll
        for (int j = 0; j < 4; ++j) acc[i][j] = (floatx4){0.f,0.f,0.f,0.f};

    bf16x8 rW[2], rX[2];
#pragma unroll
    for (int r = 0; r < 2; ++r) {
        rW[r] = *(const bf16x8*)&W[(size_t)(ob + srow[r]) * 256 + scg];
        rX[r] = *(const bf16x8*)&XT[((size_t)b * SEQ + n0 + srow[r]) * 256 + scg];
    }
#pragma unroll
    for (int r = 0; r < 2; ++r) {
        *(bf16x8*)&smem[0][srow[r]*40 + scg]           = rW[r];
        *(bf16x8*)&smem[0][128*40 + srow[r]*40 + scg]  = rX[r];
    }
    __syncthreads();

    int p = 0;
    for (int kc = 0; kc < 8; ++kc) {
        const bool pre = (kc + 1 < 8);
        if (pre) {
            const int k1 = (kc + 1) * 32;
#pragma unroll
            for (int r = 0; r < 2; ++r) {
                rW[r] = *(const bf16x8*)&W[(size_t)(ob + srow[r]) * 256 + k1 + scg];
                rX[r] = *(const bf16x8*)&XT[((size_t)b * SEQ + n0 + srow[r]) * 256 + k1 + scg];
            }
        }
        bf16x8 aF[4], bF[4];
        const int kq = quad * 8;
#pragma unroll
        for (int mt = 0; mt < 4; ++mt)
            aF[mt] = *(const bf16x8*)&smem[p][(wm*64 + mt*16 + lrow)*40 + kq];
#pragma unroll
        for (int nt = 0; nt < 4; ++nt)
            bF[nt] = *(const bf16x8*)&smem[p][128*40 + (wn*64 + nt*16 + lrow)*40 + kq];
#pragma unroll
        for (int mt = 0; mt < 4; ++mt)
#pragma unroll
            for (int nt = 0; nt < 4; ++nt)
                acc[mt][nt] = MFMA(aF[mt], bF[nt], acc[mt][nt]);
        if (pre) {
#pragma unroll
            for (int r = 0; r < 2; ++r) {
                *(bf16x8*)&smem[p^1][srow[r]*40 + scg]          = rW[r];
                *(bf16x8*)&smem[p^1][128*40 + srow[r]*40 + scg] = rX[r];
            }
        }
        __syncthreads();
        p ^= 1;
    }
    const float osc = (mode == 0) ? SCALE_LOG2 : 1.0f;
    if (mode == 2) {
        // v layout: [bh][d][m].  Stage [64 o][128 n] halves in LDS, then write
        // bf16x8 rows (16 lanes cover 256 contiguous bytes of n).
        for (int half = 0; half < 2; ++half) {
            __syncthreads();
            if (wm == half) {
#pragma unroll
                for (int mt = 0; mt < 4; ++mt)
#pragma unroll
                    for (int j = 0; j < 4; ++j) {
                        int ol = mt*16 + quad*4 + j;         // 0..63
                        float bvv = bias[ob + half*64 + ol];
#pragma unroll
                        for (int nt = 0; nt < 4; ++nt) {
                            int n = wn*64 + nt*16 + lrow;    // 0..127
                            stage2[ol*132 + n] = f2bf(acc[mt][nt][j] + bvv);
                        }
                    }
            }
            __syncthreads();
#pragma unroll
            for (int i = 0; i < 4; ++i) {
                int c = i * 256 + t;                         // 0..1023
                int row = c >> 4, sub = c & 15;              // row 0..63, sub 0..15
                int o = ob + half*64 + row;
                int d = o >> 2, h = o & 3;
                *(bf16x8*)&out[((size_t)(b*HEADS + h) * HD + d) * SEQ + n0 + sub*8] =
                    *(const bf16x8*)&stage2[row*132 + sub*8];
            }
        }
        return;
    }
    for (int half = 0; half < 2; ++half) {
        __syncthreads();
        if (wm == half) {
#pragma unroll
            for (int mt = 0; mt < 4; ++mt)
#pragma unroll
                for (int j = 0; j < 4; ++j) {
                    int o = ob + half*64 + mt*16 + quad*4 + j;
                    float bvv = bias[o];
                    int col = j*16 + mt*4 + quad;
#pragma unroll
                    for (int nt = 0; nt < 4; ++nt) {
                        int n = wn*64 + nt*16 + lrow;
                        stage[n][col] = f2bf((acc[mt][nt][j] + bvv) * osc);
                    }
                }
        }
        __syncthreads();
#pragma unroll
        for (int i = 0; i < 4; ++i) {
            int c = i * 256 + t;
            int n = c >> 3, h = (c >> 1) & 3, sub = c & 1;
            bf16x8 val = *(const bf16x8*)&stage[n][h*16 + sub*8];
            int d0 = (ob >> 2) + half*16 + sub*8;
            *(bf16x8*)&out[((size_t)(b*HEADS + h) * SEQ + n0 + n) * HD + d0] = val;
        }
    }
}

// ---------------------------------------------------------------------------
// Flash attention, transposed-softmax, m-split, double-buffered LDS.
// grid (16*MCHUNKS, SEQ/256) = (32, 16): 512 blocks, 2/CU.
// R14 (verified R6: 97->72.6us, MfmaUtil 45%): 64 q-rows/wave so every K/V
//     LDS read feeds 4 MFMAs; padded-72 layout; launch_bounds(256,2).
//     MFMA-busy ~33us ~= the 31us floor; leave structure alone.
// ---------------------------------------------------------------------------
__global__ __launch_bounds__(256, 2) void flash_attn(
        const unsigned short* __restrict__ q,
        const unsigned short* __restrict__ k,
        const unsigned short* __restrict__ v,
        unsigned short* __restrict__ poO, float* __restrict__ pol)
{
    __shared__ unsigned short smem[2][9216];   // per buf: lK 64x72 then lV 64x72
    const int t = threadIdx.x, lane = t & 63, wid = t >> 6;
    const int lrow = lane & 15, quad = lane >> 4;
    const int bc = blockIdx.x, qt = blockIdx.y;
    const int bh = bc & 15, chunk = bc >> 4;
    const int hb = (bh & 3) * BATCH + (bh >> 2);
    const int r0 = qt * 256 + wid * 64;

    bf16x8 qf[4][2];
#pragma unroll
    for (int nh = 0; nh < 4; ++nh) {
        const size_t base = ((size_t)bh * SEQ + r0 + nh*16 + lrow) * HD;
        qf[nh][0] = *(const bf16x8*)&q[base + quad * 8];
        qf[nh][1] = *(const bf16x8*)&q[base + 32 + quad * 8];
    }
    bf16x8 ones;
#pragma unroll
    for (int i = 0; i < 8; ++i) ones[i] = (short)0x3F80;  // bf16 1.0
    int mmv[2], cgv[2], krv[2];
#pragma unroll
    for (int r = 0; r < 2; ++r) {
        int linear = r * 256 + t;
        int mm = linear >> 3, cg = (linear & 7) * 8;
        int c2 = mm >> 5, mp = mm & 31;
        mmv[r] = mm; cgv[r] = cg;
        krv[r] = (c2 << 5) + ((mp & 4) << 2) + ((mp >> 3) << 2) + (mp & 3);
    }
    const size_t kbase = ((size_t)bh * SEQ + chunk * (SEQ/MCHUNKS));
    const size_t vbase = (size_t)bh * HD;
    const int moff = chunk * (SEQ/MCHUNKS);
    const int NIT = SEQ / MCHUNKS / 64;

    floatx4 oacc[4][4], oaccL[4];
#pragma unroll
    for (int nh = 0; nh < 4; ++nh) {
        oaccL[nh] = (floatx4){0.f,0.f,0.f,0.f};
#pragma unroll
        for (int i = 0; i < 4; ++i) oacc[nh][i] = (floatx4){0.f,0.f,0.f,0.f};
    }

    {
        bf16x8 pk[2], pv[2];
#pragma unroll
        for (int r = 0; r < 2; ++r) {
            pk[r] = *(const bf16x8*)&k[(kbase + mmv[r]) * HD + cgv[r]];
            pv[r] = *(const bf16x8*)&v[(vbase + mmv[r]) * SEQ + moff + cgv[r]];
        }
#pragma unroll
        for (int r = 0; r < 2; ++r) {
            *(bf16x8*)&smem[0][krv[r]*72 + cgv[r]]        = pk[r];
            *(bf16x8*)&smem[0][4608 + mmv[r]*72 + cgv[r]] = pv[r];
        }
    }
    __syncthreads();

    int p = 0;
#pragma unroll 1
    for (int it = 0; it < NIT; ++it) {
        bf16x8 pk[2], pv[2];
        const bool pre = (it + 1 < NIT);
        if (pre) {
            const int m1 = (it + 1) * 64;
#pragma unroll
            for (int r = 0; r < 2; ++r) {
                pk[r] = *(const bf16x8*)&k[(kbase + m1 + mmv[r]) * HD + cgv[r]];
                pv[r] = *(const bf16x8*)&v[(vbase + mmv[r]) * SEQ + moff + m1 + cgv[r]];
            }
        }
        const unsigned short* lS = smem[p];

#pragma unroll
        for (int c2 = 0; c2 < 2; ++c2) {
            floatx4 sa[2][4];
#pragma unroll
            for (int AB = 0; AB < 2; ++AB)
#pragma unroll
                for (int nh = 0; nh < 4; ++nh)
                    sa[AB][nh] = (floatx4){0.f,0.f,0.f,0.f};
            __builtin_amdgcn_s_setprio(1);
#pragma unroll
            for (int AB = 0; AB < 2; ++AB) {
#pragma unroll
                for (int kc = 0; kc < 2; ++kc) {
                    bf16x8 kf = *(const bf16x8*)&lS[(c2*32 + AB*16 + lrow)*72 + kc*32 + quad*8];
#pragma unroll
                    for (int nh = 0; nh < 4; ++nh)
                        sa[AB][nh] = MFMA(kf, qf[nh][kc], sa[AB][nh]);
                }
            }
            __builtin_amdgcn_s_setprio(0);
            bf16x8 pf8[4];
#pragma unroll
            for (int nh = 0; nh < 4; ++nh) {
                floatx4 ea, eb;
#pragma unroll
                for (int i = 0; i < 4; ++i) { ea[i] = EXP2(sa[0][nh][i]); eb[i] = EXP2(sa[1][nh][i]); }
                pf8[nh] = pack_bf16x8(ea, eb);
            }
            __builtin_amdgcn_s_setprio(1);
#pragma unroll
            for (int nh = 0; nh < 4; ++nh)
                oaccL[nh] = MFMA(ones, pf8[nh], oaccL[nh]);
#pragma unroll
            for (int dt = 0; dt < 4; ++dt) {
                bf16x8 vf = *(const bf16x8*)&lS[4608 + (dt*16 + lrow)*72 + c2*32 + quad*8];
#pragma unroll
                for (int nh = 0; nh < 4; ++nh)
                    oacc[nh][dt] = MFMA(vf, pf8[nh], oacc[nh][dt]);
            }
            __builtin_amdgcn_s_setprio(0);
        }
        if (pre) {
#pragma unroll
            for (int r = 0; r < 2; ++r) {
                *(bf16x8*)&smem[p^1][krv[r]*72 + cgv[r]]        = pk[r];
                *(bf16x8*)&smem[p^1][4608 + mmv[r]*72 + cgv[r]] = pv[r];
            }
        }
        __syncthreads();
        p ^= 1;
    }
    const size_t prow = (size_t)(chunk*16 + hb) * SEQ + qt * 256;
    if (lane < 16) {
#pragma unroll
        for (int nh = 0; nh < 4; ++nh)
            pol[prow + wid*64 + nh*16 + lrow] = oaccL[nh][0];
    }
    // epilogue: packed b64 stores, [256][72] staging (uses both LDS buffers)
    unsigned short* stB = (unsigned short*)&smem[0][0];
#pragma unroll
    for (int nh = 0; nh < 4; ++nh)
#pragma unroll
        for (int dt = 0; dt < 4; ++dt) {
            bf16x4 pv4 = pack_bf16x4(oacc[nh][dt][0], oacc[nh][dt][1],
                                     oacc[nh][dt][2], oacc[nh][dt][3]);
            *(bf16x4*)&stB[(wid*64 + nh*16 + lrow)*72 + dt*16 + quad*4] = pv4;
        }
    __syncthreads();
#pragma unroll
    for (int i = 0; i < 8; ++i) {
        int c = i * 256 + t;
        int row = c >> 3, sub = c & 7;
        *(bf16x8*)&poO[(prow + row) * HD + sub*8] = *(const bf16x8*)&stB[row*72 + sub*8];
    }
}

// ---------------------------------------------------------------------------
// combine_o (R15): attnC[pos][256] = (poO_c0 + poO_c1) * inv(l).  One pass,
// removes the 4x-redundant poO combine from gemm_mlp1's prefetch path.
// grid (NPOS/32) = 512 blocks; traffic 16MB read + 8MB write.
// ---------------------------------------------------------------------------
__global__ __launch_bounds__(256) void combine_o(
        const unsigned short* __restrict__ poO, const float* __restrict__ pol,
        unsigned short* __restrict__ attnC)
{
    const int t = threadIdx.x;
    const int p0 = blockIdx.x * 32;
    const size_t CH = (size_t)16 * SEQ * HD;   // chunk stride in poO
#pragma unroll
    for (int i = 0; i < 4; ++i) {
        int g = i * 256 + t;            // 0..1023: bf16x8 group
        int pl = g >> 5;                // 0..31 local pos
        int cg = (g & 31) * 8;          // 0..248 channel start
        int pos = p0 + pl;
        int b = pos >> 12, n = pos & (SEQ - 1);
        int h = cg >> 6, d0 = cg & 63;
        int hb = h * BATCH + b;
        const unsigned short* bse = &poO[((size_t)hb * SEQ + n) * HD + d0];
        float l0 = pol[(size_t)hb * SEQ + n];
        float l1 = pol[(size_t)(16 + hb) * SEQ + n];
        float inv = 1.0f / (l0 + l1);
        bf16x8 a0 = *(const bf16x8*)bse;
        bf16x8 a1 = *(const bf16x8*)(bse + CH);
        unsigned short res[8];
#pragma unroll
        for (int j = 0; j < 8; ++j)
            res[j] = f2bf((bf2f((unsigned short)a0[j]) + bf2f((unsigned short)a1[j])) * inv);
        *(bf16x8*)&attnC[(size_t)pos * 256 + cg] = *(const bf16x8*)res;
    }
}

// ---------------------------------------------------------------------------
// mlp1 (merge folded, LDS double-buffered, 1 barrier/iter, 128-o tiles):
// h1[pos][512] = xT@w1b[:,0:256]^T + attnC@w1f^T + b1f.  R15: attnC is
// precombined (combine_o) so both A-sources are plain [pos][256] bf16 loads —
// no per-iter combine VALU, no sInv/pol.  Fused BN stats atomics.
// grid (4, NPOS/64), block 256.
// ---------------------------------------------------------------------------
__global__ __launch_bounds__(256) void gemm_mlp1(
        const unsigned short* __restrict__ xT, const unsigned short* __restrict__ attnC,
        const unsigned short* __restrict__ w1b, const unsigned short* __restrict__ w1f,
        const float* __restrict__ b1f, unsigned short* __restrict__ h1,
        float* __restrict__ sums, float* __restrict__ sumsq)
{
    __shared__ unsigned short lA[2][64][40];
    __shared__ unsigned short lB[2][128][40];
    const int t = threadIdx.x;
    const int lane = t & 63, wid = t >> 6;
    const int wm = wid >> 1, wn = wid & 1;
    const int lrow = lane & 15, quad = lane >> 4;
    const int o0 = blockIdx.x * 128;
    const int p0 = blockIdx.y * 64;

    const int arow = t >> 2, acg = (t & 3) * 8;
    const int brow[2] = { (0*256 + t) >> 2, (1*256 + t) >> 2 };

    floatx4 acc[2][4];
#pragma unroll
    for (int i = 0; i < 2; ++i)
#pragma unroll
        for (int j = 0; j < 4; ++j) acc[i][j] = (floatx4){0.f,0.f,0.f,0.f};

    bf16x8 rA, rB[2];
    auto load_tile = [&](int k0) {
        if (k0 < 256) {
            rA = *(const bf16x8*)&xT[(size_t)(p0 + arow) * 256 + k0 + acg];
#pragma unroll
            for (int r = 0; r < 2; ++r)
                rB[r] = *(const bf16x8*)&w1b[(size_t)(o0 + brow[r]) * 512 + k0 + acg];
        } else {
            const int kk2 = k0 - 256;
            rA = *(const bf16x8*)&attnC[(size_t)(p0 + arow) * 256 + kk2 + acg];
#pragma unroll
            for (int r = 0; r < 2; ++r)
                rB[r] = *(const bf16x8*)&w1f[(size_t)(o0 + brow[r]) * 256 + kk2 + acg];
        }
    };

    load_tile(0);
    *(bf16x8*)&lA[0][arow][acg] = rA;
#pragma unroll
    for (int r = 0; r < 2; ++r) *(bf16x8*)&lB[0][brow[r]][acg] = rB[r];
    __syncthreads();

    int p = 0;
    for (int kc = 0; kc < 16; ++kc) {
        const bool pre = (kc + 1 < 16);
        if (pre) load_tile((kc + 1) * 32);
        bf16x8 aF[2], bF[4];
        const int kq = quad * 8;
#pragma unroll
        for (int mt = 0; mt < 2; ++mt)
            aF[mt] = *(const bf16x8*)&lA[p][wm*32 + mt*16 + lrow][kq];
#pragma unroll
        for (int nt = 0; nt < 4; ++nt)
            bF[nt] = *(const bf16x8*)&lB[p][wn*64 + nt*16 + lrow][kq];
#pragma unroll
        for (int mt = 0; mt < 2; ++mt)
#pragma unroll
            for (int nt = 0; nt < 4; ++nt)
                acc[mt][nt] = MFMA(aF[mt], bF[nt], acc[mt][nt]);
        if (pre) {
            *(bf16x8*)&lA[p^1][arow][acg] = rA;
#pragma unroll
            for (int r = 0; r < 2; ++r) *(bf16x8*)&lB[p^1][brow[r]][acg] = rB[r];
        }
        __syncthreads();
        p ^= 1;
    }
#pragma unroll
    for (int nt = 0; nt < 4; ++nt) {
        int o = o0 + wn*64 + nt*16 + lrow;
        float bvv = b1f[o];
        float s = 0.f, qs = 0.f;
#pragma unroll
        for (int mt = 0; mt < 2; ++mt)
#pragma unroll
            for (int j = 0; j < 4; ++j) {
                int pos = p0 + wm*32 + mt*16 + quad*4 + j;
                float val = acc[mt][nt][j] + bvv;
                h1[(size_t)pos * 512 + o] = f2bf(val);
                s += val; qs += val * val;
            }
        s  += __shfl_xor(s, 16);  s  += __shfl_xor(s, 32);
        qs += __shfl_xor(qs, 16); qs += __shfl_xor(qs, 32);
        if (lane < 16) {
            atomicAdd(&sums[o], s);
            atomicAdd(&sumsq[o], qs);
        }
    }
}

// ---------------------------------------------------------------------------
// mlp2 (bf16 W, inline bn_final, LDS double-buffered):
// out[b][o][n] f32 = W2 @ relu(bn(h1))^T + bias. grid (2, NPOS/64).
// ---------------------------------------------------------------------------
__global__ __launch_bounds__(256) void gemm_mlp2(
        const unsigned short* __restrict__ W2, const unsigned short* __restrict__ h1,
        const float* __restrict__ bias,
        const float* __restrict__ sums, const float* __restrict__ sumsq,
        const float* __restrict__ gamma, const float* __restrict__ beta,
        float* __restrict__ out)
{
    __shared__ unsigned short lA[2][128][40];
    __shared__ unsigned short lB[2][64][40];
    __shared__ float sSc[512], sSh[512];
    const int t = threadIdx.x;
    const int lane = t & 63, wid = t >> 6;
    const int wm = wid >> 1, wn = wid & 1;
    const int lrow = lane & 15, quad = lane >> 4;
    const int o0 = blockIdx.x * 128;
    const int p0 = blockIdx.y * 64;

#pragma unroll
    for (int cc = 0; cc < 2; ++cc) {
        int c = cc * 256 + t;
        float mean = sums[c] * (1.0f / NPOS);
        float var  = sumsq[c] * (1.0f / NPOS) - mean * mean;
        float sc = gamma[c] * rsqrtf(var + 1e-5f);
        sSc[c] = sc;
        sSh[c] = beta[c] - mean * sc;
    }
    __syncthreads();

    const int arow[2] = { (0*256 + t) >> 2, (1*256 + t) >> 2 };
    const int acg = (t & 3) * 8;
    const int brow = t >> 2;

    floatx4 acc[4][2];
#pragma unroll
    for (int i = 0; i < 4; ++i)
#pragma unroll
        for (int j = 0; j < 2; ++j) acc[i][j] = (floatx4){0.f,0.f,0.f,0.f};

    bf16x8 rW[2], rH;
    auto load_tile = [&](int k0) {
#pragma unroll
        for (int r = 0; r < 2; ++r)
            rW[r] = *(const bf16x8*)&W2[(size_t)(o0 + arow[r]) * 512 + k0 + acg];
        bf16x8 hv = *(const bf16x8*)&h1[(size_t)(p0 + brow) * 512 + k0 + acg];
        unsigned short res[8];
#pragma unroll
        for (int i = 0; i < 8; ++i) {
            int c = k0 + acg + i;
            float f = bf2f((unsigned short)hv[i]);
            f = fmaxf(f * sSc[c] + sSh[c], 0.f);
            res[i] = f2bf(f);
        }
        rH = *(const bf16x8*)res;
    };

    load_tile(0);
#pragma unroll
    for (int r = 0; r < 2; ++r) *(bf16x8*)&lA[0][arow[r]][acg] = rW[r];
    *(bf16x8*)&lB[0][brow][acg] = rH;
    __syncthreads();

    int p = 0;
    for (int kc = 0; kc < 16; ++kc) {
        const bool pre = (kc + 1 < 16);
        if (pre) load_tile((kc + 1) * 32);
        bf16x8 aF[4], bF[2];
        const int kq = quad * 8;
#pragma unroll
        for (int mt = 0; mt < 4; ++mt)
            aF[mt] = *(const bf16x8*)&lA[p][wm*64 + mt*16 + lrow][kq];
#pragma unroll
        for (int nt = 0; nt < 2; ++nt)
            bF[nt] = *(const bf16x8*)&lB[p][wn*32 + nt*16 + lrow][kq];
#pragma unroll
        for (int mt = 0; mt < 4; ++mt)
#pragma unroll
            for (int nt = 0; nt < 2; ++nt)
                acc[mt][nt] = MFMA(aF[mt], bF[nt], acc[mt][nt]);
        if (pre) {
#pragma unroll
            for (int r = 0; r < 2; ++r) *(bf16x8*)&lA[p^1][arow[r]][acg] = rW[r];
            *(bf16x8*)&lB[p^1][brow][acg] = rH;
        }
        __syncthreads();
        p ^= 1;
    }
#pragma unroll
    for (int mt = 0; mt < 4; ++mt)
#pragma unroll
        for (int j = 0; j < 4; ++j) {
            int o = o0 + wm*64 + mt*16 + quad*4 + j;
            float bvv = bias[o];
#pragma unroll
            for (int nt = 0; nt < 2; ++nt) {
                int pos = p0 + wn*32 + nt*16 + lrow;
                int b = pos >> 12, n = pos & (SEQ - 1);
                out[((size_t)b * D_MODEL + o) * SEQ + n] = acc[mt][nt][j] + bvv;
            }
        }
}

// ---------------------------------------------------------------------------
extern "C" void kernel_launch(void* const* d_in, const int* in_sizes, int n_in,
                              void* d_out, int out_size, void* d_ws, size_t ws_size,
                              hipStream_t stream)
{
    (void)in_sizes; (void)n_in; (void)out_size; (void)ws_size;
    const float* x        = (const float*)d_in[0];
    const float* source   = (const float*)d_in[1];
    const float* pq_w     = (const float*)d_in[2];
    const float* pq_b     = (const float*)d_in[3];
    const float* pk_w     = (const float*)d_in[4];
    const float* pk_b     = (const float*)d_in[5];
    const float* pv_w     = (const float*)d_in[6];
    const float* pv_b     = (const float*)d_in[7];
    const float* merge_w  = (const float*)d_in[8];
    const float* merge_b  = (const float*)d_in[9];
    const float* mlp1_w   = (const float*)d_in[10];
    const float* mlp1_b   = (const float*)d_in[11];
    const float* bn_gamma = (const float*)d_in[12];
    const float* bn_beta  = (const float*)d_in[13];
    const float* mlp2_w   = (const float*)d_in[14];
    const float* mlp2_b   = (const float*)d_in[15];
    float* out = (float*)d_out;

    char* ws = (char*)d_ws;
    const size_t MB = 1ull << 20;
    unsigned short* xT   = (unsigned short*)(ws);             //  8 MB [pos][256]
    unsigned short* srcT = (unsigned short*)(ws + 8*MB);      //  8 MB [pos][256]
    unsigned short* q    = (unsigned short*)(ws + 16*MB);     //  8 MB [bh][n][64]
    unsigned short* kk   = (unsigned short*)(ws + 24*MB);     //  8 MB [bh][m][64]
    unsigned short* v    = (unsigned short*)(ws + 32*MB);     //  8 MB [bh][64][m]
    unsigned short* poO  = (unsigned short*)(ws + 40*MB);     // 16 MB bf16 partial O (MCHUNKS=2)
    unsigned short* attnC= (unsigned short*)(ws + 56*MB);     //  8 MB combined O [pos][256]
    unsigned short* h1   = (unsigned short*)(ws + 16*MB);     // 16 MB [pos][512] — aliases q+kk (dead post-flash)
    float* pol = (float*)(ws + 72*MB);                        // 512 KB partial l (32 rows)
    unsigned short* wqb = (unsigned short*)(ws + 73*MB);
    unsigned short* wkb = wqb + 65536;
    unsigned short* wvb = wkb + 65536;
    unsigned short* wmt = wvb + 65536;                        // [c'][o] 128 KB
    unsigned short* w1b = wmt + 65536;                        // 512 KB full mlp1_w
    unsigned short* w2b = w1b + 262144;                       // 256 KB
    unsigned short* w1f = w2b + 131072;                       // 256 KB folded
    float* b1f = (float*)(w1f + 131072);                      // 512 folded bias
    float* bn_sum = b1f + 512;
    float* bn_sumsq = bn_sum + 512;

    hipMemsetAsync(bn_sum, 0, 1024 * sizeof(float), stream);

    prep<<<dim3(1152), 256, 0, stream>>>(
        pq_w, pk_w, pv_w, merge_w, mlp1_w, mlp2_w, x, source,
        wqb, wkb, wvb, wmt, w1b, w2b, xT, srcT);
    prep2<<<dim3(2, 9), 256, 0, stream>>>(mlp1_w, mlp1_b, merge_b, wmt, w1f, b1f);
    proj_qkv_all<<<dim3(6, SEQ/128, BATCH), 256, 0, stream>>>(
        wqb, pq_b, wkb, pk_b, wvb, pv_b, xT, srcT, q, kk, v);
    flash_attn<<<dim3(16*MCHUNKS, SEQ/256), 256, 0, stream>>>(q, kk, v, poO, pol);
    combine_o<<<dim3(NPOS/32), 256, 0, stream>>>(poO, pol, attnC);
    gemm_mlp1<<<dim3(4, NPOS/64), 256, 0, stream>>>(
        xT, attnC, w1b, w1f, b1f, h1, bn_sum, bn_sumsq);
    gemm_mlp2<<<dim3(2, NPOS/64), 256, 0, stream>>>(
        w2b, h1, mlp2_b, bn_sum, bn_sumsq, bn_gamma, bn_beta, out);
}

// Round 8
// 243.428 us; speedup vs baseline: 1.0537x; 1.0537x over previous
//
#include <hip/hip_runtime.h>
#include <hip/hip_bf16.h>

#define D_MODEL 256
#define HEADS 4
#define HD 64
#define BATCH 4
#define SEQ 4096
#define NPOS (BATCH*SEQ)          // 16384 positions
#define SCALE_LOG2 0.18033688011112042f  // log2(e)/8, folded into q projection
#define MCHUNKS 2                 // flash m-split (partials add; no online max)

typedef __attribute__((ext_vector_type(4))) float floatx4;
typedef __attribute__((ext_vector_type(8))) short bf16x8;
typedef __attribute__((ext_vector_type(4))) short bf16x4;
typedef __attribute__((ext_vector_type(4))) unsigned short ushortx4;

__device__ __forceinline__ float bf2f(unsigned short b) {
    return __uint_as_float(((unsigned int)b) << 16);
}
__device__ __forceinline__ unsigned short f2bf(float f) {
    unsigned int u = __float_as_uint(f);
    return (unsigned short)((u + 0x7fffu + ((u >> 16) & 1u)) >> 16);
}
__device__ __forceinline__ bf16x4 pack_bf16x4(float a, float b, float c, float d) {
    __hip_bfloat162 lo = __float22bfloat162_rn(float2{a, b});
    __hip_bfloat162 hi = __float22bfloat162_rn(float2{c, d});
    union { __hip_bfloat162 h2[2]; bf16x4 v; } u;
    u.h2[0] = lo; u.h2[1] = hi;
    return u.v;
}
__device__ __forceinline__ bf16x8 pack_bf16x8(floatx4 a, floatx4 b) {
    union { bf16x4 h[2]; bf16x8 v; } u;
    u.h[0] = pack_bf16x4(a[0], a[1], a[2], a[3]);
    u.h[1] = pack_bf16x4(b[0], b[1], b[2], b[3]);
    return u.v;
}
#define MFMA(a,b,c) __builtin_amdgcn_mfma_f32_16x16x32_bf16((a),(b),(c),0,0,0)
#define EXP2(x) __builtin_amdgcn_exp2f(x)   // native v_exp_f32 (exp2f -> ocml is ~5x slower)

// ---------------------------------------------------------------------------
// prep_all (R16: prep + prep2 + bn-zero fused into ONE dispatch; chain is now
// 5 dispatches total — the non-flash block has been invariant at ~185us across
// all rounds while per-kernel roofline sums to ~60us, implicating per-dispatch
// overhead, not kernel work).
//   blocks [0,576):      linear f32->bf16 weight copies (pq,pk,pv,mlp1,mlp2)
//   blocks [576,1088):   transpose x/source -> xT/srcT [pos][256] bf16
//   blocks [1088,1104):  merge-fold GEMM  w1f[o2][c'] = sum_o W1u[o2][o]*Wmt[c'][o]
//                        (Wmt gathered on the fly from merge_w — no staging buf)
//   blocks [1104,1106):  bias fold b1f
//   block  1106:         zero bn_sum/bn_sumsq
// ---------------------------------------------------------------------------
__global__ __launch_bounds__(256) void prep_all(
        const float* __restrict__ pq_w, const float* __restrict__ pk_w,
        const float* __restrict__ pv_w, const float* __restrict__ merge_w,
        const float* __restrict__ mlp1_w, const float* __restrict__ mlp2_w,
        const float* __restrict__ mlp1_b, const float* __restrict__ merge_b,
        const float* __restrict__ x, const float* __restrict__ src,
        unsigned short* __restrict__ wqb, unsigned short* __restrict__ wkb,
        unsigned short* __restrict__ wvb,
        unsigned short* __restrict__ w1b, unsigned short* __restrict__ w2b,
        unsigned short* __restrict__ xT, unsigned short* __restrict__ srcT,
        unsigned short* __restrict__ w1f, float* __restrict__ b1f,
        float* __restrict__ bn_zero)
{
    __shared__ unsigned short smem[64 * 264];   // transpose lT / fold lA+lB union
    const int t = threadIdx.x;
    const int bx = blockIdx.x;
    if (bx < 576) {
        int linear = bx * 1024 + t * 4;
        const float* srcW; unsigned short* dst; int off;
        if (linear < 65536)       { srcW = pq_w;   dst = wqb; off = 0; }
        else if (linear < 131072) { srcW = pk_w;   dst = wkb; off = 65536; }
        else if (linear < 196608) { srcW = pv_w;   dst = wvb; off = 131072; }
        else if (linear < 458752) { srcW = mlp1_w; dst = w1b; off = 196608; }
        else                      { srcW = mlp2_w; dst = w2b; off = 458752; }
        int i = linear - off;
        float4 w = *(const float4*)&srcW[i];
        ushortx4 s = { f2bf(w.x), f2bf(w.y), f2bf(w.z), f2bf(w.w) };
        *(ushortx4*)&dst[i] = s;
        return;
    }
    if (bx < 1088) {
        unsigned short (*lT)[264] = (unsigned short (*)[264])smem;
        int z = bx - 576;
        const float* X = (z < 256) ? x : src;
        unsigned short* O = (z < 256) ? xT : srcT;
        int rem = z & 255;
        int b = rem >> 6, n0 = (rem & 63) * 64;
#pragma unroll
        for (int r = 0; r < 16; ++r) {
            int idx = r * 256 + t;
            int ch = idx >> 4, nnq = (idx & 15) * 4;
            float4 v4 = *(const float4*)&X[((size_t)b * 256 + ch) * SEQ + n0 + nnq];
            lT[nnq + 0][ch] = f2bf(v4.x);
            lT[nnq + 1][ch] = f2bf(v4.y);
            lT[nnq + 2][ch] = f2bf(v4.z);
            lT[nnq + 3][ch] = f2bf(v4.w);
        }
        __syncthreads();
#pragma unroll
        for (int r = 0; r < 8; ++r) {
            int idx = r * 256 + t;
            int row = idx >> 5, cg = (idx & 31) * 8;
            *(bf16x8*)&O[((size_t)b * SEQ + n0 + row) * 256 + cg] = *(const bf16x8*)&lT[row][cg];
        }
        return;
    }
    if (bx < 1104) {
        // merge-fold GEMM (was prep2 y<8).  lB gathered from merge_w directly:
        // wmt[cp][o] = merge_w[o][((cp&63)<<2)|(cp>>6)]
        unsigned short (*lA)[40] = (unsigned short (*)[40])smem;
        unsigned short (*lB)[40] = (unsigned short (*)[40])(smem + 64 * 40);
        const int lane = t & 63, wid = t >> 6;
        const int wm = wid >> 1, wn = wid & 1;
        const int lrow = lane & 15, quad = lane >> 4;
        const int fb = bx - 1088;
        const int c0  = (fb & 1) * 128;
        const int o20 = (fb >> 1) * 64;

        floatx4 acc[2][4];
#pragma unroll
        for (int i = 0; i < 2; ++i)
#pragma unroll
            for (int j = 0; j < 4; ++j) acc[i][j] = (floatx4){0.f,0.f,0.f,0.f};

        for (int k0 = 0; k0 < 256; k0 += 32) {
#pragma unroll
            for (int r = 0; r < 2; ++r) {
                int linear = r * 1024 + t * 4;
                int row = linear >> 5, col = linear & 31;
                float4 w = *(const float4*)&mlp1_w[(size_t)(o20 + row) * 512 + 256 + k0 + col];
                ushortx4 s = { f2bf(w.x), f2bf(w.y), f2bf(w.z), f2bf(w.w) };
                *(ushortx4*)&lA[row][col] = s;
            }
#pragma unroll
            for (int r = 0; r < 2; ++r) {
                int linear = r * 256 + t;
                int row = linear >> 2, cg = (linear & 3) * 8;
                int cp = c0 + row;
                int pc = ((cp & 63) << 2) | (cp >> 6);
                unsigned short s[8];
#pragma unroll
                for (int j = 0; j < 8; ++j)
                    s[j] = f2bf(merge_w[(size_t)(k0 + cg + j) * 256 + pc]);
                *(bf16x8*)&lB[row][cg] = *(const bf16x8*)s;
            }
            __syncthreads();
            bf16x8 aF[2], bF[4];
            const int kq = quad * 8;
#pragma unroll
            for (int mt = 0; mt < 2; ++mt)
                aF[mt] = *(const bf16x8*)&lA[wm*32 + mt*16 + lrow][kq];
#pragma unroll
            for (int nt = 0; nt < 4; ++nt)
                bF[nt] = *(const bf16x8*)&lB[wn*64 + nt*16 + lrow][kq];
#pragma unroll
            for (int mt = 0; mt < 2; ++mt)
#pragma unroll
                for (int nt = 0; nt < 4; ++nt)
                    acc[mt][nt] = MFMA(aF[mt], bF[nt], acc[mt][nt]);
            __syncthreads();
        }
#pragma unroll
        for (int nt = 0; nt < 4; ++nt) {
            int cp = c0 + wn*64 + nt*16 + lrow;
#pragma unroll
            for (int mt = 0; mt < 2; ++mt)
#pragma unroll
                for (int j = 0; j < 4; ++j) {
                    int o2 = o20 + wm*32 + mt*16 + quad*4 + j;
                    w1f[(size_t)o2 * 256 + cp] = f2bf(acc[mt][nt][j]);
                }
        }
        return;
    }
    if (bx < 1106) {
        int o2 = (bx - 1104) * 256 + t;
        float s = mlp1_b[o2];
        for (int o = 0; o < 256; ++o)
            s += mlp1_w[(size_t)o2 * 512 + 256 + o] * merge_b[o];
        b1f[o2] = s;
        return;
    }
    // bx == 1106: zero bn_sum/bn_sumsq (1024 floats)
    *(float4*)&bn_zero[t * 4] = float4{0.f, 0.f, 0.f, 0.f};
}

// ---------------------------------------------------------------------------
// Merged QKV projection, double-buffered LDS (1 barrier/k-step).
// grid (6, SEQ/128, B): mode = x>>1 (0=q,1=k,2=v), ob = (x&1)*128.
// v-mode epilogue staged through LDS for coalesced bf16x8 stores.
// ---------------------------------------------------------------------------
__global__ __launch_bounds__(256) void proj_qkv_all(
        const unsigned short* __restrict__ Wq, const float* __restrict__ bq,
        const unsigned short* __restrict__ Wk, const float* __restrict__ bk,
        const unsigned short* __restrict__ Wv, const float* __restrict__ bv,
        const unsigned short* __restrict__ xT, const unsigned short* __restrict__ srcT,
        unsigned short* __restrict__ qo, unsigned short* __restrict__ ko,
        unsigned short* __restrict__ vo)
{
    __shared__ unsigned short smem[2][128 * 80];   // per buf: lA 128x40, lB 128x40
    unsigned short (*stage)[72] = (unsigned short (*)[72])&smem[0][0];
    unsigned short* stage2 = &smem[0][0];          // v-mode: flat [64][132] u16
    const int t = threadIdx.x;
    const int lane = t & 63, wid = t >> 6;
    const int wm = wid >> 1, wn = wid & 1;
    const int lrow = lane & 15, quad = lane >> 4;
    const int mode = blockIdx.x >> 1;
    const int ob = (blockIdx.x & 1) * 128;
    const int n0 = blockIdx.y * 128;
    const int b  = blockIdx.z;
    const unsigned short* W  = (mode == 0) ? Wq : (mode == 1) ? Wk : Wv;
    const float* bias        = (mode == 0) ? bq : (mode == 1) ? bk : bv;
    const unsigned short* XT = (mode == 0) ? xT : srcT;
    unsigned short* out      = (mode == 0) ? qo : (mode == 1) ? ko : vo;

    const int srow[2] = { (0*256 + t) >> 2, (1*256 + t) >> 2 };
    const int scg = (t & 3) * 8;

    floatx4 acc[4][4];
#pragma unroll
    for (int i = 0; i < 4; ++i)
#pragma unroll
        for (int j = 0; j < 4; ++j) acc[i][j] = (floatx4){0.f,0.f,0.f,0.f};

    bf16x8 rW[2], rX[2];
#pragma unroll
    for (int r = 0; r < 2; ++r) {
        rW[r] = *(const bf16x8*)&W[(size_t)(ob + srow[r]) * 256 + scg];
        rX[r] = *(const bf16x8*)&XT[((size_t)b * SEQ + n0 + srow[r]) * 256 + scg];
    }
#pragma unroll
    for (int r = 0; r < 2; ++r) {
        *(bf16x8*)&smem[0][srow[r]*40 + scg]           = rW[r];
        *(bf16x8*)&smem[0][128*40 + srow[r]*40 + scg]  = rX[r];
    }
    __syncthreads();

    int p = 0;
    for (int kc = 0; kc < 8; ++kc) {
        const bool pre = (kc + 1 < 8);
        if (pre) {
            const int k1 = (kc + 1) * 32;
#pragma unroll
            for (int r = 0; r < 2; ++r) {
                rW[r] = *(const bf16x8*)&W[(size_t)(ob + srow[r]) * 256 + k1 + scg];
                rX[r] = *(const bf16x8*)&XT[((size_t)b * SEQ + n0 + srow[r]) * 256 + k1 + scg];
            }
        }
        bf16x8 aF[4], bF[4];
        const int kq = quad * 8;
#pragma unroll
        for (int mt = 0; mt < 4; ++mt)
            aF[mt] = *(const bf16x8*)&smem[p][(wm*64 + mt*16 + lrow)*40 + kq];
#pragma unroll
        for (int nt = 0; nt < 4; ++nt)
            bF[nt] = *(const bf16x8*)&smem[p][128*40 + (wn*64 + nt*16 + lrow)*40 + kq];
#pragma unroll
        for (int mt = 0; mt < 4; ++mt)
#pragma unroll
            for (int nt = 0; nt < 4; ++nt)
                acc[mt][nt] = MFMA(aF[mt], bF[nt], acc[mt][nt]);
        if (pre) {
#pragma unroll
            for (int r = 0; r < 2; ++r) {
                *(bf16x8*)&smem[p^1][srow[r]*40 + scg]          = rW[r];
                *(bf16x8*)&smem[p^1][128*40 + srow[r]*40 + scg] = rX[r];
            }
        }
        __syncthreads();
        p ^= 1;
    }
    const float osc = (mode == 0) ? SCALE_LOG2 : 1.0f;
    if (mode == 2) {
        // v layout: [bh][d][m].  Stage [64 o][128 n] halves in LDS, then write
        // bf16x8 rows (16 lanes cover 256 contiguous bytes of n).
        for (int half = 0; half < 2; ++half) {
            __syncthreads();
            if (wm == half) {
#pragma unroll
                for (int mt = 0; mt < 4; ++mt)
#pragma unroll
                    for (int j = 0; j < 4; ++j) {
                        int ol = mt*16 + quad*4 + j;         // 0..63
                        float bvv = bias[ob + half*64 + ol];
#pragma unroll
                        for (int nt = 0; nt < 4; ++nt) {
                            int n = wn*64 + nt*16 + lrow;    // 0..127
                            stage2[ol*132 + n] = f2bf(acc[mt][nt][j] + bvv);
                        }
                    }
            }
            __syncthreads();
#pragma unroll
            for (int i = 0; i < 4; ++i) {
                int c = i * 256 + t;                         // 0..1023
                int row = c >> 4, sub = c & 15;              // row 0..63, sub 0..15
                int o = ob + half*64 + row;
                int d = o >> 2, h = o & 3;
                *(bf16x8*)&out[((size_t)(b*HEADS + h) * HD + d) * SEQ + n0 + sub*8] =
                    *(const bf16x8*)&stage2[row*132 + sub*8];
            }
        }
        return;
    }
    for (int half = 0; half < 2; ++half) {
        __syncthreads();
        if (wm == half) {
#pragma unroll
            for (int mt = 0; mt < 4; ++mt)
#pragma unroll
                for (int j = 0; j < 4; ++j) {
                    int o = ob + half*64 + mt*16 + quad*4 + j;
                    float bvv = bias[o];
                    int col = j*16 + mt*4 + quad;
#pragma unroll
                    for (int nt = 0; nt < 4; ++nt) {
                        int n = wn*64 + nt*16 + lrow;
                        stage[n][col] = f2bf((acc[mt][nt][j] + bvv) * osc);
                    }
                }
        }
        __syncthreads();
#pragma unroll
        for (int i = 0; i < 4; ++i) {
            int c = i * 256 + t;
            int n = c >> 3, h = (c >> 1) & 3, sub = c & 1;
            bf16x8 val = *(const bf16x8*)&stage[n][h*16 + sub*8];
            int d0 = (ob >> 2) + half*16 + sub*8;
            *(bf16x8*)&out[((size_t)(b*HEADS + h) * SEQ + n0 + n) * HD + d0] = val;
        }
    }
}

// ---------------------------------------------------------------------------
// Flash attention, transposed-softmax, m-split, double-buffered LDS.
// grid (16*MCHUNKS, SEQ/256) = (32, 16): 512 blocks, 2/CU.
// R14 (verified R6/R7: 72us, MfmaUtil 45%): 64 q-rows/wave so every K/V
//     LDS read feeds 4 MFMAs; padded-72 layout; launch_bounds(256,2).
//     MFMA-busy ~33us ~= the 31us floor; structure frozen.
// ---------------------------------------------------------------------------
__global__ __launch_bounds__(256, 2) void flash_attn(
        const unsigned short* __restrict__ q,
        const unsigned short* __restrict__ k,
        const unsigned short* __restrict__ v,
        unsigned short* __restrict__ poO, float* __restrict__ pol)
{
    __shared__ unsigned short smem[2][9216];   // per buf: lK 64x72 then lV 64x72
    const int t = threadIdx.x, lane = t & 63, wid = t >> 6;
    const int lrow = lane & 15, quad = lane >> 4;
    const int bc = blockIdx.x, qt = blockIdx.y;
    const int bh = bc & 15, chunk = bc >> 4;
    const int hb = (bh & 3) * BATCH + (bh >> 2);
    const int r0 = qt * 256 + wid * 64;

    bf16x8 qf[4][2];
#pragma unroll
    for (int nh = 0; nh < 4; ++nh) {
        const size_t base = ((size_t)bh * SEQ + r0 + nh*16 + lrow) * HD;
        qf[nh][0] = *(const bf16x8*)&q[base + quad * 8];
        qf[nh][1] = *(const bf16x8*)&q[base + 32 + quad * 8];
    }
    bf16x8 ones;
#pragma unroll
    for (int i = 0; i < 8; ++i) ones[i] = (short)0x3F80;  // bf16 1.0
    int mmv[2], cgv[2], krv[2];
#pragma unroll
    for (int r = 0; r < 2; ++r) {
        int linear = r * 256 + t;
        int mm = linear >> 3, cg = (linear & 7) * 8;
        int c2 = mm >> 5, mp = mm & 31;
        mmv[r] = mm; cgv[r] = cg;
        krv[r] = (c2 << 5) + ((mp & 4) << 2) + ((mp >> 3) << 2) + (mp & 3);
    }
    const size_t kbase = ((size_t)bh * SEQ + chunk * (SEQ/MCHUNKS));
    const size_t vbase = (size_t)bh * HD;
    const int moff = chunk * (SEQ/MCHUNKS);
    const int NIT = SEQ / MCHUNKS / 64;

    floatx4 oacc[4][4], oaccL[4];
#pragma unroll
    for (int nh = 0; nh < 4; ++nh) {
        oaccL[nh] = (floatx4){0.f,0.f,0.f,0.f};
#pragma unroll
        for (int i = 0; i < 4; ++i) oacc[nh][i] = (floatx4){0.f,0.f,0.f,0.f};
    }

    {
        bf16x8 pk[2], pv[2];
#pragma unroll
        for (int r = 0; r < 2; ++r) {
            pk[r] = *(const bf16x8*)&k[(kbase + mmv[r]) * HD + cgv[r]];
            pv[r] = *(const bf16x8*)&v[(vbase + mmv[r]) * SEQ + moff + cgv[r]];
        }
#pragma unroll
        for (int r = 0; r < 2; ++r) {
            *(bf16x8*)&smem[0][krv[r]*72 + cgv[r]]        = pk[r];
            *(bf16x8*)&smem[0][4608 + mmv[r]*72 + cgv[r]] = pv[r];
        }
    }
    __syncthreads();

    int p = 0;
#pragma unroll 1
    for (int it = 0; it < NIT; ++it) {
        bf16x8 pk[2], pv[2];
        const bool pre = (it + 1 < NIT);
        if (pre) {
            const int m1 = (it + 1) * 64;
#pragma unroll
            for (int r = 0; r < 2; ++r) {
                pk[r] = *(const bf16x8*)&k[(kbase + m1 + mmv[r]) * HD + cgv[r]];
                pv[r] = *(const bf16x8*)&v[(vbase + mmv[r]) * SEQ + moff + m1 + cgv[r]];
            }
        }
        const unsigned short* lS = smem[p];

#pragma unroll
        for (int c2 = 0; c2 < 2; ++c2) {
            floatx4 sa[2][4];
#pragma unroll
            for (int AB = 0; AB < 2; ++AB)
#pragma unroll
                for (int nh = 0; nh < 4; ++nh)
                    sa[AB][nh] = (floatx4){0.f,0.f,0.f,0.f};
            __builtin_amdgcn_s_setprio(1);
#pragma unroll
            for (int AB = 0; AB < 2; ++AB) {
#pragma unroll
                for (int kc = 0; kc < 2; ++kc) {
                    bf16x8 kf = *(const bf16x8*)&lS[(c2*32 + AB*16 + lrow)*72 + kc*32 + quad*8];
#pragma unroll
                    for (int nh = 0; nh < 4; ++nh)
                        sa[AB][nh] = MFMA(kf, qf[nh][kc], sa[AB][nh]);
                }
            }
            __builtin_amdgcn_s_setprio(0);
            bf16x8 pf8[4];
#pragma unroll
            for (int nh = 0; nh < 4; ++nh) {
                floatx4 ea, eb;
#pragma unroll
                for (int i = 0; i < 4; ++i) { ea[i] = EXP2(sa[0][nh][i]); eb[i] = EXP2(sa[1][nh][i]); }
                pf8[nh] = pack_bf16x8(ea, eb);
            }
            __builtin_amdgcn_s_setprio(1);
#pragma unroll
            for (int nh = 0; nh < 4; ++nh)
                oaccL[nh] = MFMA(ones, pf8[nh], oaccL[nh]);
#pragma unroll
            for (int dt = 0; dt < 4; ++dt) {
                bf16x8 vf = *(const bf16x8*)&lS[4608 + (dt*16 + lrow)*72 + c2*32 + quad*8];
#pragma unroll
                for (int nh = 0; nh < 4; ++nh)
                    oacc[nh][dt] = MFMA(vf, pf8[nh], oacc[nh][dt]);
            }
            __builtin_amdgcn_s_setprio(0);
        }
        if (pre) {
#pragma unroll
            for (int r = 0; r < 2; ++r) {
                *(bf16x8*)&smem[p^1][krv[r]*72 + cgv[r]]        = pk[r];
                *(bf16x8*)&smem[p^1][4608 + mmv[r]*72 + cgv[r]] = pv[r];
            }
        }
        __syncthreads();
        p ^= 1;
    }
    const size_t prow = (size_t)(chunk*16 + hb) * SEQ + qt * 256;
    if (lane < 16) {
#pragma unroll
        for (int nh = 0; nh < 4; ++nh)
            pol[prow + wid*64 + nh*16 + lrow] = oaccL[nh][0];
    }
    // epilogue: packed b64 stores, [256][72] staging (uses both LDS buffers)
    unsigned short* stB = (unsigned short*)&smem[0][0];
#pragma unroll
    for (int nh = 0; nh < 4; ++nh)
#pragma unroll
        for (int dt = 0; dt < 4; ++dt) {
            bf16x4 pv4 = pack_bf16x4(oacc[nh][dt][0], oacc[nh][dt][1],
                                     oacc[nh][dt][2], oacc[nh][dt][3]);
            *(bf16x4*)&stB[(wid*64 + nh*16 + lrow)*72 + dt*16 + quad*4] = pv4;
        }
    __syncthreads();
#pragma unroll
    for (int i = 0; i < 8; ++i) {
        int c = i * 256 + t;
        int row = c >> 3, sub = c & 7;
        *(bf16x8*)&poO[(prow + row) * HD + sub*8] = *(const bf16x8*)&stB[row*72 + sub*8];
    }
}

// ---------------------------------------------------------------------------
// mlp1 (R16: reverted to R6 structure — in-kernel poO combine; R7's split-out
// combine_o kernel was net-negative).  LDS double-buffered, 1 barrier/iter:
// h1[pos][512] = xT@w1b[:,0:256]^T + attnC'@w1f^T + b1f;  attnC' combined
// on the fly from MCHUNKS bf16 poO partials + pol.  Fused BN stats atomics.
// grid (4, NPOS/64), block 256.
// ---------------------------------------------------------------------------
__global__ __launch_bounds__(256) void gemm_mlp1(
        const unsigned short* __restrict__ xT, const unsigned short* __restrict__ poO,
        const float* __restrict__ pol,
        const unsigned short* __restrict__ w1b, const unsigned short* __restrict__ w1f,
        const float* __restrict__ b1f, unsigned short* __restrict__ h1,
        float* __restrict__ sums, float* __restrict__ sumsq)
{
    __shared__ unsigned short lA[2][64][40];
    __shared__ unsigned short lB[2][128][40];
    __shared__ float sInv[256];
    const int t = threadIdx.x;
    const int lane = t & 63, wid = t >> 6;
    const int wm = wid >> 1, wn = wid & 1;
    const int lrow = lane & 15, quad = lane >> 4;
    const int o0 = blockIdx.x * 128;
    const int p0 = blockIdx.y * 64;
    const int b = p0 >> 12, n0 = p0 & (SEQ - 1);
    const size_t CH = (size_t)16 * SEQ * HD;

    {
        int h = t >> 6, nn = t & 63;
        int hb = h * BATCH + b;
        float l = 0.f;
#pragma unroll
        for (int c = 0; c < MCHUNKS; ++c)
            l += pol[((size_t)(c*16 + hb)) * SEQ + n0 + nn];
        sInv[t] = 1.0f / l;
    }
    __syncthreads();

    const int arow = t >> 2, acg = (t & 3) * 8;
    const int brow[2] = { (0*256 + t) >> 2, (1*256 + t) >> 2 };

    floatx4 acc[2][4];
#pragma unroll
    for (int i = 0; i < 2; ++i)
#pragma unroll
        for (int j = 0; j < 4; ++j) acc[i][j] = (floatx4){0.f,0.f,0.f,0.f};

    bf16x8 rA, rB[2];
    auto load_tile = [&](int k0) {
        if (k0 < 256) {
            rA = *(const bf16x8*)&xT[(size_t)(p0 + arow) * 256 + k0 + acg];
#pragma unroll
            for (int r = 0; r < 2; ++r)
                rB[r] = *(const bf16x8*)&w1b[(size_t)(o0 + brow[r]) * 512 + k0 + acg];
        } else {
            const int kk2 = k0 - 256;
            const int h = kk2 >> 6, d0 = kk2 & 63, hb = h * BATCH + b;
            const unsigned short* bse = &poO[((size_t)hb * SEQ + n0 + arow) * HD + d0 + acg];
            float inv = sInv[h*64 + arow];
            float fs[8];
#pragma unroll
            for (int i = 0; i < 8; ++i) fs[i] = 0.f;
#pragma unroll
            for (int c = 0; c < MCHUNKS; ++c) {
                bf16x8 a = *(const bf16x8*)(bse + (size_t)c * CH);
#pragma unroll
                for (int i = 0; i < 8; ++i)
                    fs[i] += bf2f((unsigned short)a[i]);
            }
            unsigned short res[8];
#pragma unroll
            for (int i = 0; i < 8; ++i)
                res[i] = f2bf(fs[i] * inv);
            rA = *(const bf16x8*)res;
#pragma unroll
            for (int r = 0; r < 2; ++r)
                rB[r] = *(const bf16x8*)&w1f[(size_t)(o0 + brow[r]) * 256 + kk2 + acg];
        }
    };

    load_tile(0);
    *(bf16x8*)&lA[0][arow][acg] = rA;
#pragma unroll
    for (int r = 0; r < 2; ++r) *(bf16x8*)&lB[0][brow[r]][acg] = rB[r];
    __syncthreads();

    int p = 0;
    for (int kc = 0; kc < 16; ++kc) {
        const bool pre = (kc + 1 < 16);
        if (pre) load_tile((kc + 1) * 32);
        bf16x8 aF[2], bF[4];
        const int kq = quad * 8;
#pragma unroll
        for (int mt = 0; mt < 2; ++mt)
            aF[mt] = *(const bf16x8*)&lA[p][wm*32 + mt*16 + lrow][kq];
#pragma unroll
        for (int nt = 0; nt < 4; ++nt)
            bF[nt] = *(const bf16x8*)&lB[p][wn*64 + nt*16 + lrow][kq];
#pragma unroll
        for (int mt = 0; mt < 2; ++mt)
#pragma unroll
            for (int nt = 0; nt < 4; ++nt)
                acc[mt][nt] = MFMA(aF[mt], bF[nt], acc[mt][nt]);
        if (pre) {
            *(bf16x8*)&lA[p^1][arow][acg] = rA;
#pragma unroll
            for (int r = 0; r < 2; ++r) *(bf16x8*)&lB[p^1][brow[r]][acg] = rB[r];
        }
        __syncthreads();
        p ^= 1;
    }
#pragma unroll
    for (int nt = 0; nt < 4; ++nt) {
        int o = o0 + wn*64 + nt*16 + lrow;
        float bvv = b1f[o];
        float s = 0.f, qs = 0.f;
#pragma unroll
        for (int mt = 0; mt < 2; ++mt)
#pragma unroll
            for (int j = 0; j < 4; ++j) {
                int pos = p0 + wm*32 + mt*16 + quad*4 + j;
                float val = acc[mt][nt][j] + bvv;
                h1[(size_t)pos * 512 + o] = f2bf(val);
                s += val; qs += val * val;
            }
        s  += __shfl_xor(s, 16);  s  += __shfl_xor(s, 32);
        qs += __shfl_xor(qs, 16); qs += __shfl_xor(qs, 32);
        if (lane < 16) {
            atomicAdd(&sums[o], s);
            atomicAdd(&sumsq[o], qs);
        }
    }
}

// ---------------------------------------------------------------------------
// mlp2 (bf16 W, inline bn_final, LDS double-buffered):
// out[b][o][n] f32 = W2 @ relu(bn(h1))^T + bias. grid (2, NPOS/64).
// ---------------------------------------------------------------------------
__global__ __launch_bounds__(256) void gemm_mlp2(
        const unsigned short* __restrict__ W2, const unsigned short* __restrict__ h1,
        const float* __restrict__ bias,
        const float* __restrict__ sums, const float* __restrict__ sumsq,
        const float* __restrict__ gamma, const float* __restrict__ beta,
        float* __restrict__ out)
{
    __shared__ unsigned short lA[2][128][40];
    __shared__ unsigned short lB[2][64][40];
    __shared__ float sSc[512], sSh[512];
    const int t = threadIdx.x;
    const int lane = t & 63, wid = t >> 6;
    const int wm = wid >> 1, wn = wid & 1;
    const int lrow = lane & 15, quad = lane >> 4;
    const int o0 = blockIdx.x * 128;
    const int p0 = blockIdx.y * 64;

#pragma unroll
    for (int cc = 0; cc < 2; ++cc) {
        int c = cc * 256 + t;
        float mean = sums[c] * (1.0f / NPOS);
        float var  = sumsq[c] * (1.0f / NPOS) - mean * mean;
        float sc = gamma[c] * rsqrtf(var + 1e-5f);
        sSc[c] = sc;
        sSh[c] = beta[c] - mean * sc;
    }
    __syncthreads();

    const int arow[2] = { (0*256 + t) >> 2, (1*256 + t) >> 2 };
    const int acg = (t & 3) * 8;
    const int brow = t >> 2;

    floatx4 acc[4][2];
#pragma unroll
    for (int i = 0; i < 4; ++i)
#pragma unroll
        for (int j = 0; j < 2; ++j) acc[i][j] = (floatx4){0.f,0.f,0.f,0.f};

    bf16x8 rW[2], rH;
    auto load_tile = [&](int k0) {
#pragma unroll
        for (int r = 0; r < 2; ++r)
            rW[r] = *(const bf16x8*)&W2[(size_t)(o0 + arow[r]) * 512 + k0 + acg];
        bf16x8 hv = *(const bf16x8*)&h1[(size_t)(p0 + brow) * 512 + k0 + acg];
        unsigned short res[8];
#pragma unroll
        for (int i = 0; i < 8; ++i) {
            int c = k0 + acg + i;
            float f = bf2f((unsigned short)hv[i]);
            f = fmaxf(f * sSc[c] + sSh[c], 0.f);
            res[i] = f2bf(f);
        }
        rH = *(const bf16x8*)res;
    };

    load_tile(0);
#pragma unroll
    for (int r = 0; r < 2; ++r) *(bf16x8*)&lA[0][arow[r]][acg] = rW[r];
    *(bf16x8*)&lB[0][brow][acg] = rH;
    __syncthreads();

    int p = 0;
    for (int kc = 0; kc < 16; ++kc) {
        const bool pre = (kc + 1 < 16);
        if (pre) load_tile((kc + 1) * 32);
        bf16x8 aF[4], bF[2];
        const int kq = quad * 8;
#pragma unroll
        for (int mt = 0; mt < 4; ++mt)
            aF[mt] = *(const bf16x8*)&lA[p][wm*64 + mt*16 + lrow][kq];
#pragma unroll
        for (int nt = 0; nt < 2; ++nt)
            bF[nt] = *(const bf16x8*)&lB[p][wn*32 + nt*16 + lrow][kq];
#pragma unroll
        for (int mt = 0; mt < 4; ++mt)
#pragma unroll
            for (int nt = 0; nt < 2; ++nt)
                acc[mt][nt] = MFMA(aF[mt], bF[nt], acc[mt][nt]);
        if (pre) {
#pragma unroll
            for (int r = 0; r < 2; ++r) *(bf16x8*)&lA[p^1][arow[r]][acg] = rW[r];
            *(bf16x8*)&lB[p^1][brow][acg] = rH;
        }
        __syncthreads();
        p ^= 1;
    }
#pragma unroll
    for (int mt = 0; mt < 4; ++mt)
#pragma unroll
        for (int j = 0; j < 4; ++j) {
            int o = o0 + wm*64 + mt*16 + quad*4 + j;
            float bvv = bias[o];
#pragma unroll
            for (int nt = 0; nt < 2; ++nt) {
                int pos = p0 + wn*32 + nt*16 + lrow;
                int b = pos >> 12, n = pos & (SEQ - 1);
                out[((size_t)b * D_MODEL + o) * SEQ + n] = acc[mt][nt][j] + bvv;
            }
        }
}

// ---------------------------------------------------------------------------
extern "C" void kernel_launch(void* const* d_in, const int* in_sizes, int n_in,
                              void* d_out, int out_size, void* d_ws, size_t ws_size,
                              hipStream_t stream)
{
    (void)in_sizes; (void)n_in; (void)out_size; (void)ws_size;
    const float* x        = (const float*)d_in[0];
    const float* source   = (const float*)d_in[1];
    const float* pq_w     = (const float*)d_in[2];
    const float* pq_b     = (const float*)d_in[3];
    const float* pk_w     = (const float*)d_in[4];
    const float* pk_b     = (const float*)d_in[5];
    const float* pv_w     = (const float*)d_in[6];
    const float* pv_b     = (const float*)d_in[7];
    const float* merge_w  = (const float*)d_in[8];
    const float* merge_b  = (const float*)d_in[9];
    const float* mlp1_w   = (const float*)d_in[10];
    const float* mlp1_b   = (const float*)d_in[11];
    const float* bn_gamma = (const float*)d_in[12];
    const float* bn_beta  = (const float*)d_in[13];
    const float* mlp2_w   = (const float*)d_in[14];
    const float* mlp2_b   = (const float*)d_in[15];
    float* out = (float*)d_out;

    char* ws = (char*)d_ws;
    const size_t MB = 1ull << 20;
    unsigned short* xT   = (unsigned short*)(ws);             //  8 MB [pos][256]
    unsigned short* srcT = (unsigned short*)(ws + 8*MB);      //  8 MB [pos][256]
    unsigned short* q    = (unsigned short*)(ws + 16*MB);     //  8 MB [bh][n][64]
    unsigned short* kk   = (unsigned short*)(ws + 24*MB);     //  8 MB [bh][m][64]
    unsigned short* v    = (unsigned short*)(ws + 32*MB);     //  8 MB [bh][64][m]
    unsigned short* poO  = (unsigned short*)(ws + 40*MB);     // 16 MB bf16 partial O (MCHUNKS=2)
    unsigned short* h1   = (unsigned short*)(ws + 16*MB);     // 16 MB [pos][512] — aliases q+kk (dead post-flash)
    float* pol = (float*)(ws + 72*MB);                        // 512 KB partial l (32 rows)
    unsigned short* wqb = (unsigned short*)(ws + 73*MB);
    unsigned short* wkb = wqb + 65536;
    unsigned short* wvb = wkb + 65536;
    unsigned short* w1b = wvb + 65536;                        // 512 KB full mlp1_w
    unsigned short* w2b = w1b + 262144;                       // 256 KB
    unsigned short* w1f = w2b + 131072;                       // 256 KB folded
    float* b1f = (float*)(w1f + 131072);                      // 512 folded bias
    float* bn_sum = b1f + 512;
    float* bn_sumsq = bn_sum + 512;

    prep_all<<<dim3(1107), 256, 0, stream>>>(
        pq_w, pk_w, pv_w, merge_w, mlp1_w, mlp2_w, mlp1_b, merge_b, x, source,
        wqb, wkb, wvb, w1b, w2b, xT, srcT, w1f, b1f, bn_sum);
    proj_qkv_all<<<dim3(6, SEQ/128, BATCH), 256, 0, stream>>>(
        wqb, pq_b, wkb, pk_b, wvb, pv_b, xT, srcT, q, kk, v);
    flash_attn<<<dim3(16*MCHUNKS, SEQ/256), 256, 0, stream>>>(q, kk, v, poO, pol);
    gemm_mlp1<<<dim3(4, NPOS/64), 256, 0, stream>>>(
        xT, poO, pol, w1b, w1f, b1f, h1, bn_sum, bn_sumsq);
    gemm_mlp2<<<dim3(2, NPOS/64), 256, 0, stream>>>(
        w2b, h1, mlp2_b, bn_sum, bn_sumsq, bn_gamma, bn_beta, out);
}

// Round 9
// 239.770 us; speedup vs baseline: 1.0698x; 1.0153x over previous
//
#include <hip/hip_runtime.h>
#include <hip/hip_bf16.h>

#define D_MODEL 256
#define HEADS 4
#define HD 64
#define BATCH 4
#define SEQ 4096
#define NPOS (BATCH*SEQ)          // 16384 positions
#define SCALE_LOG2 0.18033688011112042f  // log2(e)/8, folded into q projection
#define MCHUNKS 2                 // flash m-split (partials add; no online max)

typedef __attribute__((ext_vector_type(4))) float floatx4;
typedef __attribute__((ext_vector_type(8))) short bf16x8;
typedef __attribute__((ext_vector_type(4))) short bf16x4;
typedef __attribute__((ext_vector_type(4))) unsigned short ushortx4;

__device__ __forceinline__ float bf2f(unsigned short b) {
    return __uint_as_float(((unsigned int)b) << 16);
}
__device__ __forceinline__ unsigned short f2bf(float f) {
    unsigned int u = __float_as_uint(f);
    return (unsigned short)((u + 0x7fffu + ((u >> 16) & 1u)) >> 16);
}
__device__ __forceinline__ bf16x4 pack_bf16x4(float a, float b, float c, float d) {
    __hip_bfloat162 lo = __float22bfloat162_rn(float2{a, b});
    __hip_bfloat162 hi = __float22bfloat162_rn(float2{c, d});
    union { __hip_bfloat162 h2[2]; bf16x4 v; } u;
    u.h2[0] = lo; u.h2[1] = hi;
    return u.v;
}
__device__ __forceinline__ bf16x8 pack_bf16x8(floatx4 a, floatx4 b) {
    union { bf16x4 h[2]; bf16x8 v; } u;
    u.h[0] = pack_bf16x4(a[0], a[1], a[2], a[3]);
    u.h[1] = pack_bf16x4(b[0], b[1], b[2], b[3]);
    return u.v;
}
#define MFMA(a,b,c) __builtin_amdgcn_mfma_f32_16x16x32_bf16((a),(b),(c),0,0,0)
#define EXP2(x) __builtin_amdgcn_exp2f(x)   // native v_exp_f32 (exp2f -> ocml is ~5x slower)

// ---------------------------------------------------------------------------
// prep_all (R16 fused dispatch; R17: bias-fold spread over 16 blocks — the
// 2-block 256-iter scalar loop was a serial tail after 1105 blocks finished).
//   blocks [0,576):      linear f32->bf16 weight copies (pq,pk,pv,mlp1,mlp2)
//   blocks [576,1088):   transpose x/source -> xT/srcT [pos][256] bf16
//   blocks [1088,1104):  merge-fold GEMM  w1f[o2][c'] = sum_o W1u[o2][o]*Wmt[c'][o]
//   blocks [1104,1120):  bias fold b1f (32 o2/block, 8 threads/o2, shfl reduce)
//   block  1120:         zero bn_sum/bn_sumsq
// ---------------------------------------------------------------------------
__global__ __launch_bounds__(256) void prep_all(
        const float* __restrict__ pq_w, const float* __restrict__ pk_w,
        const float* __restrict__ pv_w, const float* __restrict__ merge_w,
        const float* __restrict__ mlp1_w, const float* __restrict__ mlp2_w,
        const float* __restrict__ mlp1_b, const float* __restrict__ merge_b,
        const float* __restrict__ x, const float* __restrict__ src,
        unsigned short* __restrict__ wqb, unsigned short* __restrict__ wkb,
        unsigned short* __restrict__ wvb,
        unsigned short* __restrict__ w1b, unsigned short* __restrict__ w2b,
        unsigned short* __restrict__ xT, unsigned short* __restrict__ srcT,
        unsigned short* __restrict__ w1f, float* __restrict__ b1f,
        float* __restrict__ bn_zero)
{
    __shared__ unsigned short smem[64 * 264];   // transpose lT / fold lA+lB union
    const int t = threadIdx.x;
    const int bx = blockIdx.x;
    if (bx < 576) {
        int linear = bx * 1024 + t * 4;
        const float* srcW; unsigned short* dst; int off;
        if (linear < 65536)       { srcW = pq_w;   dst = wqb; off = 0; }
        else if (linear < 131072) { srcW = pk_w;   dst = wkb; off = 65536; }
        else if (linear < 196608) { srcW = pv_w;   dst = wvb; off = 131072; }
        else if (linear < 458752) { srcW = mlp1_w; dst = w1b; off = 196608; }
        else                      { srcW = mlp2_w; dst = w2b; off = 458752; }
        int i = linear - off;
        float4 w = *(const float4*)&srcW[i];
        ushortx4 s = { f2bf(w.x), f2bf(w.y), f2bf(w.z), f2bf(w.w) };
        *(ushortx4*)&dst[i] = s;
        return;
    }
    if (bx < 1088) {
        unsigned short (*lT)[264] = (unsigned short (*)[264])smem;
        int z = bx - 576;
        const float* X = (z < 256) ? x : src;
        unsigned short* O = (z < 256) ? xT : srcT;
        int rem = z & 255;
        int b = rem >> 6, n0 = (rem & 63) * 64;
#pragma unroll
        for (int r = 0; r < 16; ++r) {
            int idx = r * 256 + t;
            int ch = idx >> 4, nnq = (idx & 15) * 4;
            float4 v4 = *(const float4*)&X[((size_t)b * 256 + ch) * SEQ + n0 + nnq];
            lT[nnq + 0][ch] = f2bf(v4.x);
            lT[nnq + 1][ch] = f2bf(v4.y);
            lT[nnq + 2][ch] = f2bf(v4.z);
            lT[nnq + 3][ch] = f2bf(v4.w);
        }
        __syncthreads();
#pragma unroll
        for (int r = 0; r < 8; ++r) {
            int idx = r * 256 + t;
            int row = idx >> 5, cg = (idx & 31) * 8;
            *(bf16x8*)&O[((size_t)b * SEQ + n0 + row) * 256 + cg] = *(const bf16x8*)&lT[row][cg];
        }
        return;
    }
    if (bx < 1104) {
        // merge-fold GEMM.  lB gathered from merge_w directly:
        // wmt[cp][o] = merge_w[o][((cp&63)<<2)|(cp>>6)]
        unsigned short (*lA)[40] = (unsigned short (*)[40])smem;
        unsigned short (*lB)[40] = (unsigned short (*)[40])(smem + 64 * 40);
        const int lane = t & 63, wid = t >> 6;
        const int wm = wid >> 1, wn = wid & 1;
        const int lrow = lane & 15, quad = lane >> 4;
        const int fb = bx - 1088;
        const int c0  = (fb & 1) * 128;
        const int o20 = (fb >> 1) * 64;

        floatx4 acc[2][4];
#pragma unroll
        for (int i = 0; i < 2; ++i)
#pragma unroll
            for (int j = 0; j < 4; ++j) acc[i][j] = (floatx4){0.f,0.f,0.f,0.f};

        for (int k0 = 0; k0 < 256; k0 += 32) {
#pragma unroll
            for (int r = 0; r < 2; ++r) {
                int linear = r * 1024 + t * 4;
                int row = linear >> 5, col = linear & 31;
                float4 w = *(const float4*)&mlp1_w[(size_t)(o20 + row) * 512 + 256 + k0 + col];
                ushortx4 s = { f2bf(w.x), f2bf(w.y), f2bf(w.z), f2bf(w.w) };
                *(ushortx4*)&lA[row][col] = s;
            }
#pragma unroll
            for (int r = 0; r < 2; ++r) {
                int linear = r * 256 + t;
                int row = linear >> 2, cg = (linear & 3) * 8;
                int cp = c0 + row;
                int pc = ((cp & 63) << 2) | (cp >> 6);
                unsigned short s[8];
#pragma unroll
                for (int j = 0; j < 8; ++j)
                    s[j] = f2bf(merge_w[(size_t)(k0 + cg + j) * 256 + pc]);
                *(bf16x8*)&lB[row][cg] = *(const bf16x8*)s;
            }
            __syncthreads();
            bf16x8 aF[2], bF[4];
            const int kq = quad * 8;
#pragma unroll
            for (int mt = 0; mt < 2; ++mt)
                aF[mt] = *(const bf16x8*)&lA[wm*32 + mt*16 + lrow][kq];
#pragma unroll
            for (int nt = 0; nt < 4; ++nt)
                bF[nt] = *(const bf16x8*)&lB[wn*64 + nt*16 + lrow][kq];
#pragma unroll
            for (int mt = 0; mt < 2; ++mt)
#pragma unroll
                for (int nt = 0; nt < 4; ++nt)
                    acc[mt][nt] = MFMA(aF[mt], bF[nt], acc[mt][nt]);
            __syncthreads();
        }
#pragma unroll
        for (int nt = 0; nt < 4; ++nt) {
            int cp = c0 + wn*64 + nt*16 + lrow;
#pragma unroll
            for (int mt = 0; mt < 2; ++mt)
#pragma unroll
                for (int j = 0; j < 4; ++j) {
                    int o2 = o20 + wm*32 + mt*16 + quad*4 + j;
                    w1f[(size_t)o2 * 256 + cp] = f2bf(acc[mt][nt][j]);
                }
        }
        return;
    }
    if (bx < 1120) {
        // bias fold: 32 o2 per block, 8 threads per o2, 32 k each + shfl reduce
        int o2 = (bx - 1104) * 32 + (t >> 3);
        int kl = t & 7;
        float s = 0.f;
#pragma unroll
        for (int o = 0; o < 32; ++o)
            s += mlp1_w[(size_t)o2 * 512 + 256 + kl*32 + o] * merge_b[kl*32 + o];
        s += __shfl_xor(s, 1); s += __shfl_xor(s, 2); s += __shfl_xor(s, 4);
        if (kl == 0) b1f[o2] = mlp1_b[o2] + s;
        return;
    }
    // bx == 1120: zero bn_sum/bn_sumsq (1024 floats)
    *(float4*)&bn_zero[t * 4] = float4{0.f, 0.f, 0.f, 0.f};
}

// ---------------------------------------------------------------------------
// Merged QKV projection, double-buffered LDS (1 barrier/k-step).
// grid (6, SEQ/128, B): mode = x>>1 (0=q,1=k,2=v), ob = (x&1)*128.
// v-mode epilogue staged through LDS for coalesced bf16x8 stores.
// ---------------------------------------------------------------------------
__global__ __launch_bounds__(256) void proj_qkv_all(
        const unsigned short* __restrict__ Wq, const float* __restrict__ bq,
        const unsigned short* __restrict__ Wk, const float* __restrict__ bk,
        const unsigned short* __restrict__ Wv, const float* __restrict__ bv,
        const unsigned short* __restrict__ xT, const unsigned short* __restrict__ srcT,
        unsigned short* __restrict__ qo, unsigned short* __restrict__ ko,
        unsigned short* __restrict__ vo)
{
    __shared__ unsigned short smem[2][128 * 80];   // per buf: lA 128x40, lB 128x40
    unsigned short (*stage)[72] = (unsigned short (*)[72])&smem[0][0];
    unsigned short* stage2 = &smem[0][0];          // v-mode: flat [64][132] u16
    const int t = threadIdx.x;
    const int lane = t & 63, wid = t >> 6;
    const int wm = wid >> 1, wn = wid & 1;
    const int lrow = lane & 15, quad = lane >> 4;
    const int mode = blockIdx.x >> 1;
    const int ob = (blockIdx.x & 1) * 128;
    const int n0 = blockIdx.y * 128;
    const int b  = blockIdx.z;
    const unsigned short* W  = (mode == 0) ? Wq : (mode == 1) ? Wk : Wv;
    const float* bias        = (mode == 0) ? bq : (mode == 1) ? bk : bv;
    const unsigned short* XT = (mode == 0) ? xT : srcT;
    unsigned short* out      = (mode == 0) ? qo : (mode == 1) ? ko : vo;

    const int srow[2] = { (0*256 + t) >> 2, (1*256 + t) >> 2 };
    const int scg = (t & 3) * 8;

    floatx4 acc[4][4];
#pragma unroll
    for (int i = 0; i < 4; ++i)
#pragma unroll
        for (int j = 0; j < 4; ++j) acc[i][j] = (floatx4){0.f,0.f,0.f,0.f};

    bf16x8 rW[2], rX[2];
#pragma unroll
    for (int r = 0; r < 2; ++r) {
        rW[r] = *(const bf16x8*)&W[(size_t)(ob + srow[r]) * 256 + scg];
        rX[r] = *(const bf16x8*)&XT[((size_t)b * SEQ + n0 + srow[r]) * 256 + scg];
    }
#pragma unroll
    for (int r = 0; r < 2; ++r) {
        *(bf16x8*)&smem[0][srow[r]*40 + scg]           = rW[r];
        *(bf16x8*)&smem[0][128*40 + srow[r]*40 + scg]  = rX[r];
    }
    __syncthreads();

    int p = 0;
    for (int kc = 0; kc < 8; ++kc) {
        const bool pre = (kc + 1 < 8);
        if (pre) {
            const int k1 = (kc + 1) * 32;
#pragma unroll
            for (int r = 0; r < 2; ++r) {
                rW[r] = *(const bf16x8*)&W[(size_t)(ob + srow[r]) * 256 + k1 + scg];
                rX[r] = *(const bf16x8*)&XT[((size_t)b * SEQ + n0 + srow[r]) * 256 + k1 + scg];
            }
        }
        bf16x8 aF[4], bF[4];
        const int kq = quad * 8;
#pragma unroll
        for (int mt = 0; mt < 4; ++mt)
            aF[mt] = *(const bf16x8*)&smem[p][(wm*64 + mt*16 + lrow)*40 + kq];
#pragma unroll
        for (int nt = 0; nt < 4; ++nt)
            bF[nt] = *(const bf16x8*)&smem[p][128*40 + (wn*64 + nt*16 + lrow)*40 + kq];
#pragma unroll
        for (int mt = 0; mt < 4; ++mt)
#pragma unroll
            for (int nt = 0; nt < 4; ++nt)
                acc[mt][nt] = MFMA(aF[mt], bF[nt], acc[mt][nt]);
        if (pre) {
#pragma unroll
            for (int r = 0; r < 2; ++r) {
                *(bf16x8*)&smem[p^1][srow[r]*40 + scg]          = rW[r];
                *(bf16x8*)&smem[p^1][128*40 + srow[r]*40 + scg] = rX[r];
            }
        }
        __syncthreads();
        p ^= 1;
    }
    const float osc = (mode == 0) ? SCALE_LOG2 : 1.0f;
    if (mode == 2) {
        // v layout: [bh][d][m].  Stage [64 o][128 n] halves in LDS, then write
        // bf16x8 rows (16 lanes cover 256 contiguous bytes of n).
        for (int half = 0; half < 2; ++half) {
            __syncthreads();
            if (wm == half) {
#pragma unroll
                for (int mt = 0; mt < 4; ++mt)
#pragma unroll
                    for (int j = 0; j < 4; ++j) {
                        int ol = mt*16 + quad*4 + j;         // 0..63
                        float bvv = bias[ob + half*64 + ol];
#pragma unroll
                        for (int nt = 0; nt < 4; ++nt) {
                            int n = wn*64 + nt*16 + lrow;    // 0..127
                            stage2[ol*132 + n] = f2bf(acc[mt][nt][j] + bvv);
                        }
                    }
            }
            __syncthreads();
#pragma unroll
            for (int i = 0; i < 4; ++i) {
                int c = i * 256 + t;                         // 0..1023
                int row = c >> 4, sub = c & 15;              // row 0..63, sub 0..15
                int o = ob + half*64 + row;
                int d = o >> 2, h = o & 3;
                *(bf16x8*)&out[((size_t)(b*HEADS + h) * HD + d) * SEQ + n0 + sub*8] =
                    *(const bf16x8*)&stage2[row*132 + sub*8];
            }
        }
        return;
    }
    for (int half = 0; half < 2; ++half) {
        __syncthreads();
        if (wm == half) {
#pragma unroll
            for (int mt = 0; mt < 4; ++mt)
#pragma unroll
                for (int j = 0; j < 4; ++j) {
                    int o = ob + half*64 + mt*16 + quad*4 + j;
                    float bvv = bias[o];
                    int col = j*16 + mt*4 + quad;
#pragma unroll
                    for (int nt = 0; nt < 4; ++nt) {
                        int n = wn*64 + nt*16 + lrow;
                        stage[n][col] = f2bf((acc[mt][nt][j] + bvv) * osc);
                    }
                }
        }
        __syncthreads();
#pragma unroll
        for (int i = 0; i < 4; ++i) {
            int c = i * 256 + t;
            int n = c >> 3, h = (c >> 1) & 3, sub = c & 1;
            bf16x8 val = *(const bf16x8*)&stage[n][h*16 + sub*8];
            int d0 = (ob >> 2) + half*16 + sub*8;
            *(bf16x8*)&out[((size_t)(b*HEADS + h) * SEQ + n0 + n) * HD + d0] = val;
        }
    }
}

// ---------------------------------------------------------------------------
// Flash attention, transposed-softmax, m-split, double-buffered LDS.
// grid (16*MCHUNKS, SEQ/256) = (32, 16): 512 blocks, 2/CU.
// R14 (verified R6/R7/R8: ~73us, MfmaUtil 45%): 64 q-rows/wave so every K/V
//     LDS read feeds 4 MFMAs; padded-72 layout; launch_bounds(256,2).
//     MFMA-busy ~33us ~= the 31us floor; structure frozen.
// ---------------------------------------------------------------------------
__global__ __launch_bounds__(256, 2) void flash_attn(
        const unsigned short* __restrict__ q,
        const unsigned short* __restrict__ k,
        const unsigned short* __restrict__ v,
        unsigned short* __restrict__ poO, float* __restrict__ pol)
{
    __shared__ unsigned short smem[2][9216];   // per buf: lK 64x72 then lV 64x72
    const int t = threadIdx.x, lane = t & 63, wid = t >> 6;
    const int lrow = lane & 15, quad = lane >> 4;
    const int bc = blockIdx.x, qt = blockIdx.y;
    const int bh = bc & 15, chunk = bc >> 4;
    const int hb = (bh & 3) * BATCH + (bh >> 2);
    const int r0 = qt * 256 + wid * 64;

    bf16x8 qf[4][2];
#pragma unroll
    for (int nh = 0; nh < 4; ++nh) {
        const size_t base = ((size_t)bh * SEQ + r0 + nh*16 + lrow) * HD;
        qf[nh][0] = *(const bf16x8*)&q[base + quad * 8];
        qf[nh][1] = *(const bf16x8*)&q[base + 32 + quad * 8];
    }
    bf16x8 ones;
#pragma unroll
    for (int i = 0; i < 8; ++i) ones[i] = (short)0x3F80;  // bf16 1.0
    int mmv[2], cgv[2], krv[2];
#pragma unroll
    for (int r = 0; r < 2; ++r) {
        int linear = r * 256 + t;
        int mm = linear >> 3, cg = (linear & 7) * 8;
        int c2 = mm >> 5, mp = mm & 31;
        mmv[r] = mm; cgv[r] = cg;
        krv[r] = (c2 << 5) + ((mp & 4) << 2) + ((mp >> 3) << 2) + (mp & 3);
    }
    const size_t kbase = ((size_t)bh * SEQ + chunk * (SEQ/MCHUNKS));
    const size_t vbase = (size_t)bh * HD;
    const int moff = chunk * (SEQ/MCHUNKS);
    const int NIT = SEQ / MCHUNKS / 64;

    floatx4 oacc[4][4], oaccL[4];
#pragma unroll
    for (int nh = 0; nh < 4; ++nh) {
        oaccL[nh] = (floatx4){0.f,0.f,0.f,0.f};
#pragma unroll
        for (int i = 0; i < 4; ++i) oacc[nh][i] = (floatx4){0.f,0.f,0.f,0.f};
    }

    {
        bf16x8 pk[2], pv[2];
#pragma unroll
        for (int r = 0; r < 2; ++r) {
            pk[r] = *(const bf16x8*)&k[(kbase + mmv[r]) * HD + cgv[r]];
            pv[r] = *(const bf16x8*)&v[(vbase + mmv[r]) * SEQ + moff + cgv[r]];
        }
#pragma unroll
        for (int r = 0; r < 2; ++r) {
            *(bf16x8*)&smem[0][krv[r]*72 + cgv[r]]        = pk[r];
            *(bf16x8*)&smem[0][4608 + mmv[r]*72 + cgv[r]] = pv[r];
        }
    }
    __syncthreads();

    int p = 0;
#pragma unroll 1
    for (int it = 0; it < NIT; ++it) {
        bf16x8 pk[2], pv[2];
        const bool pre = (it + 1 < NIT);
        if (pre) {
            const int m1 = (it + 1) * 64;
#pragma unroll
            for (int r = 0; r < 2; ++r) {
                pk[r] = *(const bf16x8*)&k[(kbase + m1 + mmv[r]) * HD + cgv[r]];
                pv[r] = *(const bf16x8*)&v[(vbase + mmv[r]) * SEQ + moff + m1 + cgv[r]];
            }
        }
        const unsigned short* lS = smem[p];

#pragma unroll
        for (int c2 = 0; c2 < 2; ++c2) {
            floatx4 sa[2][4];
#pragma unroll
            for (int AB = 0; AB < 2; ++AB)
#pragma unroll
                for (int nh = 0; nh < 4; ++nh)
                    sa[AB][nh] = (floatx4){0.f,0.f,0.f,0.f};
            __builtin_amdgcn_s_setprio(1);
#pragma unroll
            for (int AB = 0; AB < 2; ++AB) {
#pragma unroll
                for (int kc = 0; kc < 2; ++kc) {
                    bf16x8 kf = *(const bf16x8*)&lS[(c2*32 + AB*16 + lrow)*72 + kc*32 + quad*8];
#pragma unroll
                    for (int nh = 0; nh < 4; ++nh)
                        sa[AB][nh] = MFMA(kf, qf[nh][kc], sa[AB][nh]);
                }
            }
            __builtin_amdgcn_s_setprio(0);
            bf16x8 pf8[4];
#pragma unroll
            for (int nh = 0; nh < 4; ++nh) {
                floatx4 ea, eb;
#pragma unroll
                for (int i = 0; i < 4; ++i) { ea[i] = EXP2(sa[0][nh][i]); eb[i] = EXP2(sa[1][nh][i]); }
                pf8[nh] = pack_bf16x8(ea, eb);
            }
            __builtin_amdgcn_s_setprio(1);
#pragma unroll
            for (int nh = 0; nh < 4; ++nh)
                oaccL[nh] = MFMA(ones, pf8[nh], oaccL[nh]);
#pragma unroll
            for (int dt = 0; dt < 4; ++dt) {
                bf16x8 vf = *(const bf16x8*)&lS[4608 + (dt*16 + lrow)*72 + c2*32 + quad*8];
#pragma unroll
                for (int nh = 0; nh < 4; ++nh)
                    oacc[nh][dt] = MFMA(vf, pf8[nh], oacc[nh][dt]);
            }
            __builtin_amdgcn_s_setprio(0);
        }
        if (pre) {
#pragma unroll
            for (int r = 0; r < 2; ++r) {
                *(bf16x8*)&smem[p^1][krv[r]*72 + cgv[r]]        = pk[r];
                *(bf16x8*)&smem[p^1][4608 + mmv[r]*72 + cgv[r]] = pv[r];
            }
        }
        __syncthreads();
        p ^= 1;
    }
    const size_t prow = (size_t)(chunk*16 + hb) * SEQ + qt * 256;
    if (lane < 16) {
#pragma unroll
        for (int nh = 0; nh < 4; ++nh)
            pol[prow + wid*64 + nh*16 + lrow] = oaccL[nh][0];
    }
    // epilogue: packed b64 stores, [256][72] staging (uses both LDS buffers)
    unsigned short* stB = (unsigned short*)&smem[0][0];
#pragma unroll
    for (int nh = 0; nh < 4; ++nh)
#pragma unroll
        for (int dt = 0; dt < 4; ++dt) {
            bf16x4 pv4 = pack_bf16x4(oacc[nh][dt][0], oacc[nh][dt][1],
                                     oacc[nh][dt][2], oacc[nh][dt][3]);
            *(bf16x4*)&stB[(wid*64 + nh*16 + lrow)*72 + dt*16 + quad*4] = pv4;
        }
    __syncthreads();
#pragma unroll
    for (int i = 0; i < 8; ++i) {
        int c = i * 256 + t;
        int row = c >> 3, sub = c & 7;
        *(bf16x8*)&poO[(prow + row) * HD + sub*8] = *(const bf16x8*)&stB[row*72 + sub*8];
    }
}

// ---------------------------------------------------------------------------
// mlp1 (R17: tile 64x128 -> 128x128, grid 512 blocks).  Per-wave output is
// now 64x64 = 16 MFMA/k-step vs 8 b128 LDS reads (ratio 2.0, was 1.33) —
// the R14 lever applied to the GEMM.  Half the blocks -> half the barrier
// waits and half the redundant poO combine traffic.
// h1[pos][512] = xT@w1b[:,0:256]^T + attnC'@w1f^T + b1f;  attnC' combined
// on the fly from MCHUNKS bf16 poO partials + pol.  Fused BN stats atomics.
// grid (4, NPOS/128), block 256.
// ---------------------------------------------------------------------------
__global__ __launch_bounds__(256) void gemm_mlp1(
        const unsigned short* __restrict__ xT, const unsigned short* __restrict__ poO,
        const float* __restrict__ pol,
        const unsigned short* __restrict__ w1b, const unsigned short* __restrict__ w1f,
        const float* __restrict__ b1f, unsigned short* __restrict__ h1,
        float* __restrict__ sums, float* __restrict__ sumsq)
{
    __shared__ unsigned short lA[2][128][40];
    __shared__ unsigned short lB[2][128][40];
    __shared__ float sInv[512];
    const int t = threadIdx.x;
    const int lane = t & 63, wid = t >> 6;
    const int wm = wid >> 1, wn = wid & 1;
    const int lrow = lane & 15, quad = lane >> 4;
    const int o0 = blockIdx.x * 128;
    const int p0 = blockIdx.y * 128;
    const int b = p0 >> 12, n0 = p0 & (SEQ - 1);
    const size_t CH = (size_t)16 * SEQ * HD;

#pragma unroll
    for (int cc = 0; cc < 2; ++cc) {
        int idx = cc * 256 + t;          // 0..511: h*128 + local pos
        int h = idx >> 7, nn = idx & 127;
        int hb = h * BATCH + b;
        float l = 0.f;
#pragma unroll
        for (int c = 0; c < MCHUNKS; ++c)
            l += pol[((size_t)(c*16 + hb)) * SEQ + n0 + nn];
        sInv[idx] = 1.0f / l;
    }
    __syncthreads();

    const int row2[2] = { (0*256 + t) >> 2, (1*256 + t) >> 2 };   // 0..127
    const int acg = (t & 3) * 8;

    floatx4 acc[4][4];
#pragma unroll
    for (int i = 0; i < 4; ++i)
#pragma unroll
        for (int j = 0; j < 4; ++j) acc[i][j] = (floatx4){0.f,0.f,0.f,0.f};

    bf16x8 rA[2], rB[2];
    auto load_tile = [&](int k0) {
        if (k0 < 256) {
#pragma unroll
            for (int r = 0; r < 2; ++r) {
                rA[r] = *(const bf16x8*)&xT[(size_t)(p0 + row2[r]) * 256 + k0 + acg];
                rB[r] = *(const bf16x8*)&w1b[(size_t)(o0 + row2[r]) * 512 + k0 + acg];
            }
        } else {
            const int kk2 = k0 - 256;
            const int h = kk2 >> 6, d0 = kk2 & 63, hb = h * BATCH + b;
#pragma unroll
            for (int r = 0; r < 2; ++r) {
                const unsigned short* bse = &poO[((size_t)hb * SEQ + n0 + row2[r]) * HD + d0 + acg];
                float inv = sInv[h*128 + row2[r]];
                float fs[8];
#pragma unroll
                for (int i = 0; i < 8; ++i) fs[i] = 0.f;
#pragma unroll
                for (int c = 0; c < MCHUNKS; ++c) {
                    bf16x8 a = *(const bf16x8*)(bse + (size_t)c * CH);
#pragma unroll
                    for (int i = 0; i < 8; ++i)
                        fs[i] += bf2f((unsigned short)a[i]);
                }
                unsigned short res[8];
#pragma unroll
                for (int i = 0; i < 8; ++i)
                    res[i] = f2bf(fs[i] * inv);
                rA[r] = *(const bf16x8*)res;
                rB[r] = *(const bf16x8*)&w1f[(size_t)(o0 + row2[r]) * 256 + kk2 + acg];
            }
        }
    };

    load_tile(0);
#pragma unroll
    for (int r = 0; r < 2; ++r) {
        *(bf16x8*)&lA[0][row2[r]][acg] = rA[r];
        *(bf16x8*)&lB[0][row2[r]][acg] = rB[r];
    }
    __syncthreads();

    int p = 0;
    for (int kc = 0; kc < 16; ++kc) {
        const bool pre = (kc + 1 < 16);
        if (pre) load_tile((kc + 1) * 32);
        bf16x8 aF[4], bF[4];
        const int kq = quad * 8;
#pragma unroll
        for (int mt = 0; mt < 4; ++mt)
            aF[mt] = *(const bf16x8*)&lA[p][wm*64 + mt*16 + lrow][kq];
#pragma unroll
        for (int nt = 0; nt < 4; ++nt)
            bF[nt] = *(const bf16x8*)&lB[p][wn*64 + nt*16 + lrow][kq];
#pragma unroll
        for (int mt = 0; mt < 4; ++mt)
#pragma unroll
            for (int nt = 0; nt < 4; ++nt)
                acc[mt][nt] = MFMA(aF[mt], bF[nt], acc[mt][nt]);
        if (pre) {
#pragma unroll
            for (int r = 0; r < 2; ++r) {
                *(bf16x8*)&lA[p^1][row2[r]][acg] = rA[r];
                *(bf16x8*)&lB[p^1][row2[r]][acg] = rB[r];
            }
        }
        __syncthreads();
        p ^= 1;
    }
#pragma unroll
    for (int nt = 0; nt < 4; ++nt) {
        int o = o0 + wn*64 + nt*16 + lrow;
        float bvv = b1f[o];
        float s = 0.f, qs = 0.f;
#pragma unroll
        for (int mt = 0; mt < 4; ++mt)
#pragma unroll
            for (int j = 0; j < 4; ++j) {
                int pos = p0 + wm*64 + mt*16 + quad*4 + j;
                float val = acc[mt][nt][j] + bvv;
                h1[(size_t)pos * 512 + o] = f2bf(val);
                s += val; qs += val * val;
            }
        s  += __shfl_xor(s, 16);  s  += __shfl_xor(s, 32);
        qs += __shfl_xor(qs, 16); qs += __shfl_xor(qs, 32);
        if (lane < 16) {
            atomicAdd(&sums[o], s);
            atomicAdd(&sumsq[o], qs);
        }
    }
}

// ---------------------------------------------------------------------------
// mlp2 (bf16 W, inline bn_final, LDS double-buffered):
// out[b][o][n] f32 = W2 @ relu(bn(h1))^T + bias. grid (2, NPOS/64).
// ---------------------------------------------------------------------------
__global__ __launch_bounds__(256) void gemm_mlp2(
        const unsigned short* __restrict__ W2, const unsigned short* __restrict__ h1,
        const float* __restrict__ bias,
        const float* __restrict__ sums, const float* __restrict__ sumsq,
        const float* __restrict__ gamma, const float* __restrict__ beta,
        float* __restrict__ out)
{
    __shared__ unsigned short lA[2][128][40];
    __shared__ unsigned short lB[2][64][40];
    __shared__ float sSc[512], sSh[512];
    const int t = threadIdx.x;
    const int lane = t & 63, wid = t >> 6;
    const int wm = wid >> 1, wn = wid & 1;
    const int lrow = lane & 15, quad = lane >> 4;
    const int o0 = blockIdx.x * 128;
    const int p0 = blockIdx.y * 64;

#pragma unroll
    for (int cc = 0; cc < 2; ++cc) {
        int c = cc * 256 + t;
        float mean = sums[c] * (1.0f / NPOS);
        float var  = sumsq[c] * (1.0f / NPOS) - mean * mean;
        float sc = gamma[c] * rsqrtf(var + 1e-5f);
        sSc[c] = sc;
        sSh[c] = beta[c] - mean * sc;
    }
    __syncthreads();

    const int arow[2] = { (0*256 + t) >> 2, (1*256 + t) >> 2 };
    const int acg = (t & 3) * 8;
    const int brow = t >> 2;

    floatx4 acc[4][2];
#pragma unroll
    for (int i = 0; i < 4; ++i)
#pragma unroll
        for (int j = 0; j < 2; ++j) acc[i][j] = (floatx4){0.f,0.f,0.f,0.f};

    bf16x8 rW[2], rH;
    auto load_tile = [&](int k0) {
#pragma unroll
        for (int r = 0; r < 2; ++r)
            rW[r] = *(const bf16x8*)&W2[(size_t)(o0 + arow[r]) * 512 + k0 + acg];
        bf16x8 hv = *(const bf16x8*)&h1[(size_t)(p0 + brow) * 512 + k0 + acg];
        unsigned short res[8];
#pragma unroll
        for (int i = 0; i < 8; ++i) {
            int c = k0 + acg + i;
            float f = bf2f((unsigned short)hv[i]);
            f = fmaxf(f * sSc[c] + sSh[c], 0.f);
            res[i] = f2bf(f);
        }
        rH = *(const bf16x8*)res;
    };

    load_tile(0);
#pragma unroll
    for (int r = 0; r < 2; ++r) *(bf16x8*)&lA[0][arow[r]][acg] = rW[r];
    *(bf16x8*)&lB[0][brow][acg] = rH;
    __syncthreads();

    int p = 0;
    for (int kc = 0; kc < 16; ++kc) {
        const bool pre = (kc + 1 < 16);
        if (pre) load_tile((kc + 1) * 32);
        bf16x8 aF[4], bF[2];
        const int kq = quad * 8;
#pragma unroll
        for (int mt = 0; mt < 4; ++mt)
            aF[mt] = *(const bf16x8*)&lA[p][wm*64 + mt*16 + lrow][kq];
#pragma unroll
        for (int nt = 0; nt < 2; ++nt)
            bF[nt] = *(const bf16x8*)&lB[p][wn*32 + nt*16 + lrow][kq];
#pragma unroll
        for (int mt = 0; mt < 4; ++mt)
#pragma unroll
            for (int nt = 0; nt < 2; ++nt)
                acc[mt][nt] = MFMA(aF[mt], bF[nt], acc[mt][nt]);
        if (pre) {
#pragma unroll
            for (int r = 0; r < 2; ++r) *(bf16x8*)&lA[p^1][arow[r]][acg] = rW[r];
            *(bf16x8*)&lB[p^1][brow][acg] = rH;
        }
        __syncthreads();
        p ^= 1;
    }
#pragma unroll
    for (int mt = 0; mt < 4; ++mt)
#pragma unroll
        for (int j = 0; j < 4; ++j) {
            int o = o0 + wm*64 + mt*16 + quad*4 + j;
            float bvv = bias[o];
#pragma unroll
            for (int nt = 0; nt < 2; ++nt) {
                int pos = p0 + wn*32 + nt*16 + lrow;
                int b = pos >> 12, n = pos & (SEQ - 1);
                out[((size_t)b * D_MODEL + o) * SEQ + n] = acc[mt][nt][j] + bvv;
            }
        }
}

// ---------------------------------------------------------------------------
extern "C" void kernel_launch(void* const* d_in, const int* in_sizes, int n_in,
                              void* d_out, int out_size, void* d_ws, size_t ws_size,
                              hipStream_t stream)
{
    (void)in_sizes; (void)n_in; (void)out_size; (void)ws_size;
    const float* x        = (const float*)d_in[0];
    const float* source   = (const float*)d_in[1];
    const float* pq_w     = (const float*)d_in[2];
    const float* pq_b     = (const float*)d_in[3];
    const float* pk_w     = (const float*)d_in[4];
    const float* pk_b     = (const float*)d_in[5];
    const float* pv_w     = (const float*)d_in[6];
    const float* pv_b     = (const float*)d_in[7];
    const float* merge_w  = (const float*)d_in[8];
    const float* merge_b  = (const float*)d_in[9];
    const float* mlp1_w   = (const float*)d_in[10];
    const float* mlp1_b   = (const float*)d_in[11];
    const float* bn_gamma = (const float*)d_in[12];
    const float* bn_beta  = (const float*)d_in[13];
    const float* mlp2_w   = (const float*)d_in[14];
    const float* mlp2_b   = (const float*)d_in[15];
    float* out = (float*)d_out;

    char* ws = (char*)d_ws;
    const size_t MB = 1ull << 20;
    unsigned short* xT   = (unsigned short*)(ws);             //  8 MB [pos][256]
    unsigned short* srcT = (unsigned short*)(ws + 8*MB);      //  8 MB [pos][256]
    unsigned short* q    = (unsigned short*)(ws + 16*MB);     //  8 MB [bh][n][64]
    unsigned short* kk   = (unsigned short*)(ws + 24*MB);     //  8 MB [bh][m][64]
    unsigned short* v    = (unsigned short*)(ws + 32*MB);     //  8 MB [bh][64][m]
    unsigned short* poO  = (unsigned short*)(ws + 40*MB);     // 16 MB bf16 partial O (MCHUNKS=2)
    unsigned short* h1   = (unsigned short*)(ws + 16*MB);     // 16 MB [pos][512] — aliases q+kk (dead post-flash)
    float* pol = (float*)(ws + 72*MB);                        // 512 KB partial l (32 rows)
    unsigned short* wqb = (unsigned short*)(ws + 73*MB);
    unsigned short* wkb = wqb + 65536;
    unsigned short* wvb = wkb + 65536;
    unsigned short* w1b = wvb + 65536;                        // 512 KB full mlp1_w
    unsigned short* w2b = w1b + 262144;                       // 256 KB
    unsigned short* w1f = w2b + 131072;                       // 256 KB folded
    float* b1f = (float*)(w1f + 131072);                      // 512 folded bias
    float* bn_sum = b1f + 512;
    float* bn_sumsq = bn_sum + 512;

    prep_all<<<dim3(1121), 256, 0, stream>>>(
        pq_w, pk_w, pv_w, merge_w, mlp1_w, mlp2_w, mlp1_b, merge_b, x, source,
        wqb, wkb, wvb, w1b, w2b, xT, srcT, w1f, b1f, bn_sum);
    proj_qkv_all<<<dim3(6, SEQ/128, BATCH), 256, 0, stream>>>(
        wqb, pq_b, wkb, pk_b, wvb, pv_b, xT, srcT, q, kk, v);
    flash_attn<<<dim3(16*MCHUNKS, SEQ/256), 256, 0, stream>>>(q, kk, v, poO, pol);
    gemm_mlp1<<<dim3(4, NPOS/128), 256, 0, stream>>>(
        xT, poO, pol, w1b, w1f, b1f, h1, bn_sum, bn_sumsq);
    gemm_mlp2<<<dim3(2, NPOS/64), 256, 0, stream>>>(
        w2b, h1, mlp2_b, bn_sum, bn_sumsq, bn_gamma, bn_beta, out);
}

// Round 10
// 238.093 us; speedup vs baseline: 1.0773x; 1.0070x over previous
//
#include <hip/hip_runtime.h>
#include <hip/hip_bf16.h>

#define D_MODEL 256
#define HEADS 4
#define HD 64
#define BATCH 4
#define SEQ 4096
#define NPOS (BATCH*SEQ)          // 16384 positions
#define SCALE_LOG2 0.18033688011112042f  // log2(e)/8, folded into q projection
#define MCHUNKS 2                 // flash m-split (partials add; no online max)

typedef __attribute__((ext_vector_type(4))) float floatx4;
typedef __attribute__((ext_vector_type(8))) short bf16x8;
typedef __attribute__((ext_vector_type(4))) short bf16x4;
typedef __attribute__((ext_vector_type(4))) unsigned short ushortx4;

__device__ __forceinline__ float bf2f(unsigned short b) {
    return __uint_as_float(((unsigned int)b) << 16);
}
__device__ __forceinline__ unsigned short f2bf(float f) {
    unsigned int u = __float_as_uint(f);
    return (unsigned short)((u + 0x7fffu + ((u >> 16) & 1u)) >> 16);
}
__device__ __forceinline__ bf16x4 pack_bf16x4(float a, float b, float c, float d) {
    __hip_bfloat162 lo = __float22bfloat162_rn(float2{a, b});
    __hip_bfloat162 hi = __float22bfloat162_rn(float2{c, d});
    union { __hip_bfloat162 h2[2]; bf16x4 v; } u;
    u.h2[0] = lo; u.h2[1] = hi;
    return u.v;
}
__device__ __forceinline__ bf16x8 pack_bf16x8(floatx4 a, floatx4 b) {
    union { bf16x4 h[2]; bf16x8 v; } u;
    u.h[0] = pack_bf16x4(a[0], a[1], a[2], a[3]);
    u.h[1] = pack_bf16x4(b[0], b[1], b[2], b[3]);
    return u.v;
}
#define MFMA(a,b,c) __builtin_amdgcn_mfma_f32_16x16x32_bf16((a),(b),(c),0,0,0)
#define EXP2(x) __builtin_amdgcn_exp2f(x)   // native v_exp_f32 (exp2f -> ocml is ~5x slower)

// ---------------------------------------------------------------------------
// prep_all (R16 fused dispatch; R17 parallel bias-fold).
//   blocks [0,576):      linear f32->bf16 weight copies (pq,pk,pv,mlp1,mlp2)
//   blocks [576,1088):   transpose x/source -> xT/srcT [pos][256] bf16
//   blocks [1088,1104):  merge-fold GEMM  w1f[o2][c'] = sum_o W1u[o2][o]*Wmt[c'][o]
//   blocks [1104,1120):  bias fold b1f (32 o2/block, 8 threads/o2, shfl reduce)
//   block  1120:         zero bn_sum/bn_sumsq
// ---------------------------------------------------------------------------
__global__ __launch_bounds__(256) void prep_all(
        const float* __restrict__ pq_w, const float* __restrict__ pk_w,
        const float* __restrict__ pv_w, const float* __restrict__ merge_w,
        const float* __restrict__ mlp1_w, const float* __restrict__ mlp2_w,
        const float* __restrict__ mlp1_b, const float* __restrict__ merge_b,
        const float* __restrict__ x, const float* __restrict__ src,
        unsigned short* __restrict__ wqb, unsigned short* __restrict__ wkb,
        unsigned short* __restrict__ wvb,
        unsigned short* __restrict__ w1b, unsigned short* __restrict__ w2b,
        unsigned short* __restrict__ xT, unsigned short* __restrict__ srcT,
        unsigned short* __restrict__ w1f, float* __restrict__ b1f,
        float* __restrict__ bn_zero)
{
    __shared__ unsigned short smem[64 * 264];   // transpose lT / fold lA+lB union
    const int t = threadIdx.x;
    const int bx = blockIdx.x;
    if (bx < 576) {
        int linear = bx * 1024 + t * 4;
        const float* srcW; unsigned short* dst; int off;
        if (linear < 65536)       { srcW = pq_w;   dst = wqb; off = 0; }
        else if (linear < 131072) { srcW = pk_w;   dst = wkb; off = 65536; }
        else if (linear < 196608) { srcW = pv_w;   dst = wvb; off = 131072; }
        else if (linear < 458752) { srcW = mlp1_w; dst = w1b; off = 196608; }
        else                      { srcW = mlp2_w; dst = w2b; off = 458752; }
        int i = linear - off;
        float4 w = *(const float4*)&srcW[i];
        ushortx4 s = { f2bf(w.x), f2bf(w.y), f2bf(w.z), f2bf(w.w) };
        *(ushortx4*)&dst[i] = s;
        return;
    }
    if (bx < 1088) {
        unsigned short (*lT)[264] = (unsigned short (*)[264])smem;
        int z = bx - 576;
        const float* X = (z < 256) ? x : src;
        unsigned short* O = (z < 256) ? xT : srcT;
        int rem = z & 255;
        int b = rem >> 6, n0 = (rem & 63) * 64;
#pragma unroll
        for (int r = 0; r < 16; ++r) {
            int idx = r * 256 + t;
            int ch = idx >> 4, nnq = (idx & 15) * 4;
            float4 v4 = *(const float4*)&X[((size_t)b * 256 + ch) * SEQ + n0 + nnq];
            lT[nnq + 0][ch] = f2bf(v4.x);
            lT[nnq + 1][ch] = f2bf(v4.y);
            lT[nnq + 2][ch] = f2bf(v4.z);
            lT[nnq + 3][ch] = f2bf(v4.w);
        }
        __syncthreads();
#pragma unroll
        for (int r = 0; r < 8; ++r) {
            int idx = r * 256 + t;
            int row = idx >> 5, cg = (idx & 31) * 8;
            *(bf16x8*)&O[((size_t)b * SEQ + n0 + row) * 256 + cg] = *(const bf16x8*)&lT[row][cg];
        }
        return;
    }
    if (bx < 1104) {
        // merge-fold GEMM.  lB gathered from merge_w directly:
        // wmt[cp][o] = merge_w[o][((cp&63)<<2)|(cp>>6)]
        unsigned short (*lA)[40] = (unsigned short (*)[40])smem;
        unsigned short (*lB)[40] = (unsigned short (*)[40])(smem + 64 * 40);
        const int lane = t & 63, wid = t >> 6;
        const int wm = wid >> 1, wn = wid & 1;
        const int lrow = lane & 15, quad = lane >> 4;
        const int fb = bx - 1088;
        const int c0  = (fb & 1) * 128;
        const int o20 = (fb >> 1) * 64;

        floatx4 acc[2][4];
#pragma unroll
        for (int i = 0; i < 2; ++i)
#pragma unroll
            for (int j = 0; j < 4; ++j) acc[i][j] = (floatx4){0.f,0.f,0.f,0.f};

        for (int k0 = 0; k0 < 256; k0 += 32) {
#pragma unroll
            for (int r = 0; r < 2; ++r) {
                int linear = r * 1024 + t * 4;
                int row = linear >> 5, col = linear & 31;
                float4 w = *(const float4*)&mlp1_w[(size_t)(o20 + row) * 512 + 256 + k0 + col];
                ushortx4 s = { f2bf(w.x), f2bf(w.y), f2bf(w.z), f2bf(w.w) };
                *(ushortx4*)&lA[row][col] = s;
            }
#pragma unroll
            for (int r = 0; r < 2; ++r) {
                int linear = r * 256 + t;
                int row = linear >> 2, cg = (linear & 3) * 8;
                int cp = c0 + row;
                int pc = ((cp & 63) << 2) | (cp >> 6);
                unsigned short s[8];
#pragma unroll
                for (int j = 0; j < 8; ++j)
                    s[j] = f2bf(merge_w[(size_t)(k0 + cg + j) * 256 + pc]);
                *(bf16x8*)&lB[row][cg] = *(const bf16x8*)s;
            }
            __syncthreads();
            bf16x8 aF[2], bF[4];
            const int kq = quad * 8;
#pragma unroll
            for (int mt = 0; mt < 2; ++mt)
                aF[mt] = *(const bf16x8*)&lA[wm*32 + mt*16 + lrow][kq];
#pragma unroll
            for (int nt = 0; nt < 4; ++nt)
                bF[nt] = *(const bf16x8*)&lB[wn*64 + nt*16 + lrow][kq];
#pragma unroll
            for (int mt = 0; mt < 2; ++mt)
#pragma unroll
                for (int nt = 0; nt < 4; ++nt)
                    acc[mt][nt] = MFMA(aF[mt], bF[nt], acc[mt][nt]);
            __syncthreads();
        }
#pragma unroll
        for (int nt = 0; nt < 4; ++nt) {
            int cp = c0 + wn*64 + nt*16 + lrow;
#pragma unroll
            for (int mt = 0; mt < 2; ++mt)
#pragma unroll
                for (int j = 0; j < 4; ++j) {
                    int o2 = o20 + wm*32 + mt*16 + quad*4 + j;
                    w1f[(size_t)o2 * 256 + cp] = f2bf(acc[mt][nt][j]);
                }
        }
        return;
    }
    if (bx < 1120) {
        // bias fold: 32 o2 per block, 8 threads per o2, 32 k each + shfl reduce
        int o2 = (bx - 1104) * 32 + (t >> 3);
        int kl = t & 7;
        float s = 0.f;
#pragma unroll
        for (int o = 0; o < 32; ++o)
            s += mlp1_w[(size_t)o2 * 512 + 256 + kl*32 + o] * merge_b[kl*32 + o];
        s += __shfl_xor(s, 1); s += __shfl_xor(s, 2); s += __shfl_xor(s, 4);
        if (kl == 0) b1f[o2] = mlp1_b[o2] + s;
        return;
    }
    // bx == 1120: zero bn_sum/bn_sumsq (1024 floats)
    *(float4*)&bn_zero[t * 4] = float4{0.f, 0.f, 0.f, 0.f};
}

// ---------------------------------------------------------------------------
// Merged QKV projection, double-buffered LDS (1 barrier/k-step).
// grid (6, SEQ/128, B): mode = x>>1 (0=q,1=k,2=v), ob = (x&1)*128.
// v-mode epilogue staged through LDS for coalesced bf16x8 stores.
// ---------------------------------------------------------------------------
__global__ __launch_bounds__(256) void proj_qkv_all(
        const unsigned short* __restrict__ Wq, const float* __restrict__ bq,
        const unsigned short* __restrict__ Wk, const float* __restrict__ bk,
        const unsigned short* __restrict__ Wv, const float* __restrict__ bv,
        const unsigned short* __restrict__ xT, const unsigned short* __restrict__ srcT,
        unsigned short* __restrict__ qo, unsigned short* __restrict__ ko,
        unsigned short* __restrict__ vo)
{
    __shared__ unsigned short smem[2][128 * 80];   // per buf: lA 128x40, lB 128x40
    unsigned short (*stage)[72] = (unsigned short (*)[72])&smem[0][0];
    unsigned short* stage2 = &smem[0][0];          // v-mode: flat [64][132] u16
    const int t = threadIdx.x;
    const int lane = t & 63, wid = t >> 6;
    const int wm = wid >> 1, wn = wid & 1;
    const int lrow = lane & 15, quad = lane >> 4;
    const int mode = blockIdx.x >> 1;
    const int ob = (blockIdx.x & 1) * 128;
    const int n0 = blockIdx.y * 128;
    const int b  = blockIdx.z;
    const unsigned short* W  = (mode == 0) ? Wq : (mode == 1) ? Wk : Wv;
    const float* bias        = (mode == 0) ? bq : (mode == 1) ? bk : bv;
    const unsigned short* XT = (mode == 0) ? xT : srcT;
    unsigned short* out      = (mode == 0) ? qo : (mode == 1) ? ko : vo;

    const int srow[2] = { (0*256 + t) >> 2, (1*256 + t) >> 2 };
    const int scg = (t & 3) * 8;

    floatx4 acc[4][4];
#pragma unroll
    for (int i = 0; i < 4; ++i)
#pragma unroll
        for (int j = 0; j < 4; ++j) acc[i][j] = (floatx4){0.f,0.f,0.f,0.f};

    bf16x8 rW[2], rX[2];
#pragma unroll
    for (int r = 0; r < 2; ++r) {
        rW[r] = *(const bf16x8*)&W[(size_t)(ob + srow[r]) * 256 + scg];
        rX[r] = *(const bf16x8*)&XT[((size_t)b * SEQ + n0 + srow[r]) * 256 + scg];
    }
#pragma unroll
    for (int r = 0; r < 2; ++r) {
        *(bf16x8*)&smem[0][srow[r]*40 + scg]           = rW[r];
        *(bf16x8*)&smem[0][128*40 + srow[r]*40 + scg]  = rX[r];
    }
    __syncthreads();

    int p = 0;
    for (int kc = 0; kc < 8; ++kc) {
        const bool pre = (kc + 1 < 8);
        if (pre) {
            const int k1 = (kc + 1) * 32;
#pragma unroll
            for (int r = 0; r < 2; ++r) {
                rW[r] = *(const bf16x8*)&W[(size_t)(ob + srow[r]) * 256 + k1 + scg];
                rX[r] = *(const bf16x8*)&XT[((size_t)b * SEQ + n0 + srow[r]) * 256 + k1 + scg];
            }
        }
        bf16x8 aF[4], bF[4];
        const int kq = quad * 8;
#pragma unroll
        for (int mt = 0; mt < 4; ++mt)
            aF[mt] = *(const bf16x8*)&smem[p][(wm*64 + mt*16 + lrow)*40 + kq];
#pragma unroll
        for (int nt = 0; nt < 4; ++nt)
            bF[nt] = *(const bf16x8*)&smem[p][128*40 + (wn*64 + nt*16 + lrow)*40 + kq];
#pragma unroll
        for (int mt = 0; mt < 4; ++mt)
#pragma unroll
            for (int nt = 0; nt < 4; ++nt)
                acc[mt][nt] = MFMA(aF[mt], bF[nt], acc[mt][nt]);
        if (pre) {
#pragma unroll
            for (int r = 0; r < 2; ++r) {
                *(bf16x8*)&smem[p^1][srow[r]*40 + scg]          = rW[r];
                *(bf16x8*)&smem[p^1][128*40 + srow[r]*40 + scg] = rX[r];
            }
        }
        __syncthreads();
        p ^= 1;
    }
    const float osc = (mode == 0) ? SCALE_LOG2 : 1.0f;
    if (mode == 2) {
        // v layout: [bh][d][m].  Stage [64 o][128 n] halves in LDS, then write
        // bf16x8 rows (16 lanes cover 256 contiguous bytes of n).
        for (int half = 0; half < 2; ++half) {
            __syncthreads();
            if (wm == half) {
#pragma unroll
                for (int mt = 0; mt < 4; ++mt)
#pragma unroll
                    for (int j = 0; j < 4; ++j) {
                        int ol = mt*16 + quad*4 + j;         // 0..63
                        float bvv = bias[ob + half*64 + ol];
#pragma unroll
                        for (int nt = 0; nt < 4; ++nt) {
                            int n = wn*64 + nt*16 + lrow;    // 0..127
                            stage2[ol*132 + n] = f2bf(acc[mt][nt][j] + bvv);
                        }
                    }
            }
            __syncthreads();
#pragma unroll
            for (int i = 0; i < 4; ++i) {
                int c = i * 256 + t;                         // 0..1023
                int row = c >> 4, sub = c & 15;              // row 0..63, sub 0..15
                int o = ob + half*64 + row;
                int d = o >> 2, h = o & 3;
                *(bf16x8*)&out[((size_t)(b*HEADS + h) * HD + d) * SEQ + n0 + sub*8] =
                    *(const bf16x8*)&stage2[row*132 + sub*8];
            }
        }
        return;
    }
    for (int half = 0; half < 2; ++half) {
        __syncthreads();
        if (wm == half) {
#pragma unroll
            for (int mt = 0; mt < 4; ++mt)
#pragma unroll
                for (int j = 0; j < 4; ++j) {
                    int o = ob + half*64 + mt*16 + quad*4 + j;
                    float bvv = bias[o];
                    int col = j*16 + mt*4 + quad;
#pragma unroll
                    for (int nt = 0; nt < 4; ++nt) {
                        int n = wn*64 + nt*16 + lrow;
                        stage[n][col] = f2bf((acc[mt][nt][j] + bvv) * osc);
                    }
                }
        }
        __syncthreads();
#pragma unroll
        for (int i = 0; i < 4; ++i) {
            int c = i * 256 + t;
            int n = c >> 3, h = (c >> 1) & 3, sub = c & 1;
            bf16x8 val = *(const bf16x8*)&stage[n][h*16 + sub*8];
            int d0 = (ob >> 2) + half*16 + sub*8;
            *(bf16x8*)&out[((size_t)(b*HEADS + h) * SEQ + n0 + n) * HD + d0] = val;
        }
    }
}

// ---------------------------------------------------------------------------
// Flash attention, transposed-softmax, m-split, double-buffered LDS.
// grid (16*MCHUNKS, SEQ/256) = (32, 16): 512 blocks, 2/CU.
// R14 (verified R6-R9: ~71us, MfmaUtil 45%): structure frozen.
// R18: poO/pol INTERLEAVED chunk layout — poO[hb][n][chunk][64],
//      pol[hb][n][chunk] — so mlp1's combine reads both partials from the
//      same 256B line pair (was 8MB apart -> 2 separate L2/L3 streams).
//      Only the epilogue store addressing changes.
// ---------------------------------------------------------------------------
__global__ __launch_bounds__(256, 2) void flash_attn(
        const unsigned short* __restrict__ q,
        const unsigned short* __restrict__ k,
        const unsigned short* __restrict__ v,
        unsigned short* __restrict__ poO, float* __restrict__ pol)
{
    __shared__ unsigned short smem[2][9216];   // per buf: lK 64x72 then lV 64x72
    const int t = threadIdx.x, lane = t & 63, wid = t >> 6;
    const int lrow = lane & 15, quad = lane >> 4;
    const int bc = blockIdx.x, qt = blockIdx.y;
    const int bh = bc & 15, chunk = bc >> 4;
    const int hb = (bh & 3) * BATCH + (bh >> 2);
    const int r0 = qt * 256 + wid * 64;

    bf16x8 qf[4][2];
#pragma unroll
    for (int nh = 0; nh < 4; ++nh) {
        const size_t base = ((size_t)bh * SEQ + r0 + nh*16 + lrow) * HD;
        qf[nh][0] = *(const bf16x8*)&q[base + quad * 8];
        qf[nh][1] = *(const bf16x8*)&q[base + 32 + quad * 8];
    }
    bf16x8 ones;
#pragma unroll
    for (int i = 0; i < 8; ++i) ones[i] = (short)0x3F80;  // bf16 1.0
    int mmv[2], cgv[2], krv[2];
#pragma unroll
    for (int r = 0; r < 2; ++r) {
        int linear = r * 256 + t;
        int mm = linear >> 3, cg = (linear & 7) * 8;
        int c2 = mm >> 5, mp = mm & 31;
        mmv[r] = mm; cgv[r] = cg;
        krv[r] = (c2 << 5) + ((mp & 4) << 2) + ((mp >> 3) << 2) + (mp & 3);
    }
    const size_t kbase = ((size_t)bh * SEQ + chunk * (SEQ/MCHUNKS));
    const size_t vbase = (size_t)bh * HD;
    const int moff = chunk * (SEQ/MCHUNKS);
    const int NIT = SEQ / MCHUNKS / 64;

    floatx4 oacc[4][4], oaccL[4];
#pragma unroll
    for (int nh = 0; nh < 4; ++nh) {
        oaccL[nh] = (floatx4){0.f,0.f,0.f,0.f};
#pragma unroll
        for (int i = 0; i < 4; ++i) oacc[nh][i] = (floatx4){0.f,0.f,0.f,0.f};
    }

    {
        bf16x8 pk[2], pv[2];
#pragma unroll
        for (int r = 0; r < 2; ++r) {
            pk[r] = *(const bf16x8*)&k[(kbase + mmv[r]) * HD + cgv[r]];
            pv[r] = *(const bf16x8*)&v[(vbase + mmv[r]) * SEQ + moff + cgv[r]];
        }
#pragma unroll
        for (int r = 0; r < 2; ++r) {
            *(bf16x8*)&smem[0][krv[r]*72 + cgv[r]]        = pk[r];
            *(bf16x8*)&smem[0][4608 + mmv[r]*72 + cgv[r]] = pv[r];
        }
    }
    __syncthreads();

    int p = 0;
#pragma unroll 1
    for (int it = 0; it < NIT; ++it) {
        bf16x8 pk[2], pv[2];
        const bool pre = (it + 1 < NIT);
        if (pre) {
            const int m1 = (it + 1) * 64;
#pragma unroll
            for (int r = 0; r < 2; ++r) {
                pk[r] = *(const bf16x8*)&k[(kbase + m1 + mmv[r]) * HD + cgv[r]];
                pv[r] = *(const bf16x8*)&v[(vbase + mmv[r]) * SEQ + moff + m1 + cgv[r]];
            }
        }
        const unsigned short* lS = smem[p];

#pragma unroll
        for (int c2 = 0; c2 < 2; ++c2) {
            floatx4 sa[2][4];
#pragma unroll
            for (int AB = 0; AB < 2; ++AB)
#pragma unroll
                for (int nh = 0; nh < 4; ++nh)
                    sa[AB][nh] = (floatx4){0.f,0.f,0.f,0.f};
            __builtin_amdgcn_s_setprio(1);
#pragma unroll
            for (int AB = 0; AB < 2; ++AB) {
#pragma unroll
                for (int kc = 0; kc < 2; ++kc) {
                    bf16x8 kf = *(const bf16x8*)&lS[(c2*32 + AB*16 + lrow)*72 + kc*32 + quad*8];
#pragma unroll
                    for (int nh = 0; nh < 4; ++nh)
                        sa[AB][nh] = MFMA(kf, qf[nh][kc], sa[AB][nh]);
                }
            }
            __builtin_amdgcn_s_setprio(0);
            bf16x8 pf8[4];
#pragma unroll
            for (int nh = 0; nh < 4; ++nh) {
                floatx4 ea, eb;
#pragma unroll
                for (int i = 0; i < 4; ++i) { ea[i] = EXP2(sa[0][nh][i]); eb[i] = EXP2(sa[1][nh][i]); }
                pf8[nh] = pack_bf16x8(ea, eb);
            }
            __builtin_amdgcn_s_setprio(1);
#pragma unroll
            for (int nh = 0; nh < 4; ++nh)
                oaccL[nh] = MFMA(ones, pf8[nh], oaccL[nh]);
#pragma unroll
            for (int dt = 0; dt < 4; ++dt) {
                bf16x8 vf = *(const bf16x8*)&lS[4608 + (dt*16 + lrow)*72 + c2*32 + quad*8];
#pragma unroll
                for (int nh = 0; nh < 4; ++nh)
                    oacc[nh][dt] = MFMA(vf, pf8[nh], oacc[nh][dt]);
            }
            __builtin_amdgcn_s_setprio(0);
        }
        if (pre) {
#pragma unroll
            for (int r = 0; r < 2; ++r) {
                *(bf16x8*)&smem[p^1][krv[r]*72 + cgv[r]]        = pk[r];
                *(bf16x8*)&smem[p^1][4608 + mmv[r]*72 + cgv[r]] = pv[r];
            }
        }
        __syncthreads();
        p ^= 1;
    }
    const size_t nb = (size_t)hb * SEQ + qt * 256;   // row base (interleaved layout)
    if (lane < 16) {
#pragma unroll
        for (int nh = 0; nh < 4; ++nh)
            pol[(nb + wid*64 + nh*16 + lrow) * MCHUNKS + chunk] = oaccL[nh][0];
    }
    // epilogue: packed b64 stores, [256][72] staging (uses both LDS buffers)
    unsigned short* stB = (unsigned short*)&smem[0][0];
#pragma unroll
    for (int nh = 0; nh < 4; ++nh)
#pragma unroll
        for (int dt = 0; dt < 4; ++dt) {
            bf16x4 pv4 = pack_bf16x4(oacc[nh][dt][0], oacc[nh][dt][1],
                                     oacc[nh][dt][2], oacc[nh][dt][3]);
            *(bf16x4*)&stB[(wid*64 + nh*16 + lrow)*72 + dt*16 + quad*4] = pv4;
        }
    __syncthreads();
#pragma unroll
    for (int i = 0; i < 8; ++i) {
        int c = i * 256 + t;
        int row = c >> 3, sub = c & 7;
        *(bf16x8*)&poO[((nb + row) * MCHUNKS + chunk) * HD + sub*8] =
            *(const bf16x8*)&stB[row*72 + sub*8];
    }
}

// ---------------------------------------------------------------------------
// mlp1 (R18: o-tile 256, 512-thread blocks, grid (2, NPOS/128) = 256 blocks).
// A-side (xT + poO) now read 2x instead of 4x (-80MB of L3 traffic); poO
// combine reads both chunks from adjacent 128B (interleaved layout).  8 waves
// (2 p-halves x 4 o-quarters), per-wave 64x64 out: 16 MFMA : 8 reads.  BN
// stats: wp-pair combined via LDS -> one atomic per (o, block) pair (65K
// total, was 131K).
// ---------------------------------------------------------------------------
__global__ __launch_bounds__(512) void gemm_mlp1(
        const unsigned short* __restrict__ xT, const unsigned short* __restrict__ poO,
        const float* __restrict__ pol,
        const unsigned short* __restrict__ w1b, const unsigned short* __restrict__ w1f,
        const float* __restrict__ b1f, unsigned short* __restrict__ h1,
        float* __restrict__ sums, float* __restrict__ sumsq)
{
    __shared__ unsigned short lA[2][128][40];
    __shared__ unsigned short lB[2][256][40];
    __shared__ float sInv[512];
    __shared__ float sRed[4][4][16][2];
    const int t = threadIdx.x;
    const int lane = t & 63, wid = t >> 6;
    const int wp = wid >> 2, wo = wid & 3;
    const int lrow = lane & 15, quad = lane >> 4;
    const int o0 = blockIdx.x * 256;
    const int p0 = blockIdx.y * 128;
    const int b = p0 >> 12, n0 = p0 & (SEQ - 1);

    {
        int h = t >> 7, nn = t & 127;          // 4 heads x 128 local pos
        int hb = h * BATCH + b;
        float2 l2 = *(const float2*)&pol[((size_t)hb * SEQ + n0 + nn) * MCHUNKS];
        sInv[t] = 1.0f / (l2.x + l2.y);
    }
    __syncthreads();

    const int arow = t >> 2, acg = (t & 3) * 8;              // 0..127
    const int brow[2] = { (0*512 + t) >> 2, (1*512 + t) >> 2 };  // 0..255

    floatx4 acc[4][4];
#pragma unroll
    for (int i = 0; i < 4; ++i)
#pragma unroll
        for (int j = 0; j < 4; ++j) acc[i][j] = (floatx4){0.f,0.f,0.f,0.f};

    bf16x8 rA, rB[2];
    auto load_tile = [&](int k0) {
        if (k0 < 256) {
            rA = *(const bf16x8*)&xT[(size_t)(p0 + arow) * 256 + k0 + acg];
#pragma unroll
            for (int r = 0; r < 2; ++r)
                rB[r] = *(const bf16x8*)&w1b[(size_t)(o0 + brow[r]) * 512 + k0 + acg];
        } else {
            const int kk2 = k0 - 256;
            const int h = kk2 >> 6, d0 = kk2 & 63, hb = h * BATCH + b;
            const unsigned short* bse =
                &poO[(((size_t)hb * SEQ + n0 + arow) * MCHUNKS) * HD + d0 + acg];
            float inv = sInv[h*128 + arow];
            bf16x8 a0 = *(const bf16x8*)bse;
            bf16x8 a1 = *(const bf16x8*)(bse + HD);          // chunk 1: +128B
            unsigned short res[8];
#pragma unroll
            for (int i = 0; i < 8; ++i)
                res[i] = f2bf((bf2f((unsigned short)a0[i]) + bf2f((unsigned short)a1[i])) * inv);
            rA = *(const bf16x8*)res;
#pragma unroll
            for (int r = 0; r < 2; ++r)
                rB[r] = *(const bf16x8*)&w1f[(size_t)(o0 + brow[r]) * 256 + kk2 + acg];
        }
    };

    load_tile(0);
    *(bf16x8*)&lA[0][arow][acg] = rA;
#pragma unroll
    for (int r = 0; r < 2; ++r) *(bf16x8*)&lB[0][brow[r]][acg] = rB[r];
    __syncthreads();

    int p = 0;
    for (int kc = 0; kc < 16; ++kc) {
        const bool pre = (kc + 1 < 16);
        if (pre) load_tile((kc + 1) * 32);
        bf16x8 aF[4], bF[4];
        const int kq = quad * 8;
#pragma unroll
        for (int mt = 0; mt < 4; ++mt)
            aF[mt] = *(const bf16x8*)&lA[p][wp*64 + mt*16 + lrow][kq];
#pragma unroll
        for (int nt = 0; nt < 4; ++nt)
            bF[nt] = *(const bf16x8*)&lB[p][wo*64 + nt*16 + lrow][kq];
#pragma unroll
        for (int mt = 0; mt < 4; ++mt)
#pragma unroll
            for (int nt = 0; nt < 4; ++nt)
                acc[mt][nt] = MFMA(aF[mt], bF[nt], acc[mt][nt]);
        if (pre) {
            *(bf16x8*)&lA[p^1][arow][acg] = rA;
#pragma unroll
            for (int r = 0; r < 2; ++r) *(bf16x8*)&lB[p^1][brow[r]][acg] = rB[r];
        }
        __syncthreads();
        p ^= 1;
    }
#pragma unroll
    for (int nt = 0; nt < 4; ++nt) {
        int o = o0 + wo*64 + nt*16 + lrow;
        float bvv = b1f[o];
        float s = 0.f, qs = 0.f;
#pragma unroll
        for (int mt = 0; mt < 4; ++mt)
#pragma unroll
            for (int j = 0; j < 4; ++j) {
                int pos = p0 + wp*64 + mt*16 + quad*4 + j;
                float val = acc[mt][nt][j] + bvv;
                h1[(size_t)pos * 512 + o] = f2bf(val);
                s += val; qs += val * val;
            }
        s  += __shfl_xor(s, 16);  s  += __shfl_xor(s, 32);
        qs += __shfl_xor(qs, 16); qs += __shfl_xor(qs, 32);
        if (wp == 1 && lane < 16) {
            sRed[wo][nt][lrow][0] = s;
            sRed[wo][nt][lrow][1] = qs;
        }
        __syncthreads();
        if (wp == 0 && lane < 16) {
            atomicAdd(&sums[o],  s  + sRed[wo][nt][lrow][0]);
            atomicAdd(&sumsq[o], qs + sRed[wo][nt][lrow][1]);
        }
    }
}

// ---------------------------------------------------------------------------
// mlp2 (bf16 W, inline bn_final, LDS double-buffered):
// out[b][o][n] f32 = W2 @ relu(bn(h1))^T + bias. grid (2, NPOS/64).
// ---------------------------------------------------------------------------
__global__ __launch_bounds__(256) void gemm_mlp2(
        const unsigned short* __restrict__ W2, const unsigned short* __restrict__ h1,
        const float* __restrict__ bias,
        const float* __restrict__ sums, const float* __restrict__ sumsq,
        const float* __restrict__ gamma, const float* __restrict__ beta,
        float* __restrict__ out)
{
    __shared__ unsigned short lA[2][128][40];
    __shared__ unsigned short lB[2][64][40];
    __shared__ float sSc[512], sSh[512];
    const int t = threadIdx.x;
    const int lane = t & 63, wid = t >> 6;
    const int wm = wid >> 1, wn = wid & 1;
    const int lrow = lane & 15, quad = lane >> 4;
    const int o0 = blockIdx.x * 128;
    const int p0 = blockIdx.y * 64;

#pragma unroll
    for (int cc = 0; cc < 2; ++cc) {
        int c = cc * 256 + t;
        float mean = sums[c] * (1.0f / NPOS);
        float var  = sumsq[c] * (1.0f / NPOS) - mean * mean;
        float sc = gamma[c] * rsqrtf(var + 1e-5f);
        sSc[c] = sc;
        sSh[c] = beta[c] - mean * sc;
    }
    __syncthreads();

    const int arow[2] = { (0*256 + t) >> 2, (1*256 + t) >> 2 };
    const int acg = (t & 3) * 8;
    const int brow = t >> 2;

    floatx4 acc[4][2];
#pragma unroll
    for (int i = 0; i < 4; ++i)
#pragma unroll
        for (int j = 0; j < 2; ++j) acc[i][j] = (floatx4){0.f,0.f,0.f,0.f};

    bf16x8 rW[2], rH;
    auto load_tile = [&](int k0) {
#pragma unroll
        for (int r = 0; r < 2; ++r)
            rW[r] = *(const bf16x8*)&W2[(size_t)(o0 + arow[r]) * 512 + k0 + acg];
        bf16x8 hv = *(const bf16x8*)&h1[(size_t)(p0 + brow) * 512 + k0 + acg];
        unsigned short res[8];
#pragma unroll
        for (int i = 0; i < 8; ++i) {
            int c = k0 + acg + i;
            float f = bf2f((unsigned short)hv[i]);
            f = fmaxf(f * sSc[c] + sSh[c], 0.f);
            res[i] = f2bf(f);
        }
        rH = *(const bf16x8*)res;
    };

    load_tile(0);
#pragma unroll
    for (int r = 0; r < 2; ++r) *(bf16x8*)&lA[0][arow[r]][acg] = rW[r];
    *(bf16x8*)&lB[0][brow][acg] = rH;
    __syncthreads();

    int p = 0;
    for (int kc = 0; kc < 16; ++kc) {
        const bool pre = (kc + 1 < 16);
        if (pre) load_tile((kc + 1) * 32);
        bf16x8 aF[4], bF[2];
        const int kq = quad * 8;
#pragma unroll
        for (int mt = 0; mt < 4; ++mt)
            aF[mt] = *(const bf16x8*)&lA[p][wm*64 + mt*16 + lrow][kq];
#pragma unroll
        for (int nt = 0; nt < 2; ++nt)
            bF[nt] = *(const bf16x8*)&lB[p][wn*32 + nt*16 + lrow][kq];
#pragma unroll
        for (int mt = 0; mt < 4; ++mt)
#pragma unroll
            for (int nt = 0; nt < 2; ++nt)
                acc[mt][nt] = MFMA(aF[mt], bF[nt], acc[mt][nt]);
        if (pre) {
#pragma unroll
            for (int r = 0; r < 2; ++r) *(bf16x8*)&lA[p^1][arow[r]][acg] = rW[r];
            *(bf16x8*)&lB[p^1][brow][acg] = rH;
        }
        __syncthreads();
        p ^= 1;
    }
#pragma unroll
    for (int mt = 0; mt < 4; ++mt)
#pragma unroll
        for (int j = 0; j < 4; ++j) {
            int o = o0 + wm*64 + mt*16 + quad*4 + j;
            float bvv = bias[o];
#pragma unroll
            for (int nt = 0; nt < 2; ++nt) {
                int pos = p0 + wn*32 + nt*16 + lrow;
                int b = pos >> 12, n = pos & (SEQ - 1);
                out[((size_t)b * D_MODEL + o) * SEQ + n] = acc[mt][nt][j] + bvv;
            }
        }
}

// ---------------------------------------------------------------------------
extern "C" void kernel_launch(void* const* d_in, const int* in_sizes, int n_in,
                              void* d_out, int out_size, void* d_ws, size_t ws_size,
                              hipStream_t stream)
{
    (void)in_sizes; (void)n_in; (void)out_size; (void)ws_size;
    const float* x        = (const float*)d_in[0];
    const float* source   = (const float*)d_in[1];
    const float* pq_w     = (const float*)d_in[2];
    const float* pq_b     = (const float*)d_in[3];
    const float* pk_w     = (const float*)d_in[4];
    const float* pk_b     = (const float*)d_in[5];
    const float* pv_w     = (const float*)d_in[6];
    const float* pv_b     = (const float*)d_in[7];
    const float* merge_w  = (const float*)d_in[8];
    const float* merge_b  = (const float*)d_in[9];
    const float* mlp1_w   = (const float*)d_in[10];
    const float* mlp1_b   = (const float*)d_in[11];
    const float* bn_gamma = (const float*)d_in[12];
    const float* bn_beta  = (const float*)d_in[13];
    const float* mlp2_w   = (const float*)d_in[14];
    const float* mlp2_b   = (const float*)d_in[15];
    float* out = (float*)d_out;

    char* ws = (char*)d_ws;
    const size_t MB = 1ull << 20;
    unsigned short* xT   = (unsigned short*)(ws);             //  8 MB [pos][256]
    unsigned short* srcT = (unsigned short*)(ws + 8*MB);      //  8 MB [pos][256]
    unsigned short* q    = (unsigned short*)(ws + 16*MB);     //  8 MB [bh][n][64]
    unsigned short* kk   = (unsigned short*)(ws + 24*MB);     //  8 MB [bh][m][64]
    unsigned short* v    = (unsigned short*)(ws + 32*MB);     //  8 MB [bh][64][m]
    unsigned short* poO  = (unsigned short*)(ws + 40*MB);     // 16 MB bf16 partial O [hb][n][chunk][64]
    unsigned short* h1   = (unsigned short*)(ws + 16*MB);     // 16 MB [pos][512] — aliases q+kk (dead post-flash)
    float* pol = (float*)(ws + 72*MB);                        // 512 KB partial l [hb][n][chunk]
    unsigned short* wqb = (unsigned short*)(ws + 73*MB);
    unsigned short* wkb = wqb + 65536;
    unsigned short* wvb = wkb + 65536;
    unsigned short* w1b = wvb + 65536;                        // 512 KB full mlp1_w
    unsigned short* w2b = w1b + 262144;                       // 256 KB
    unsigned short* w1f = w2b + 131072;                       // 256 KB folded
    float* b1f = (float*)(w1f + 131072);                      // 512 folded bias
    float* bn_sum = b1f + 512;
    float* bn_sumsq = bn_sum + 512;

    prep_all<<<dim3(1121), 256, 0, stream>>>(
        pq_w, pk_w, pv_w, merge_w, mlp1_w, mlp2_w, mlp1_b, merge_b, x, source,
        wqb, wkb, wvb, w1b, w2b, xT, srcT, w1f, b1f, bn_sum);
    proj_qkv_all<<<dim3(6, SEQ/128, BATCH), 256, 0, stream>>>(
        wqb, pq_b, wkb, pk_b, wvb, pv_b, xT, srcT, q, kk, v);
    flash_attn<<<dim3(16*MCHUNKS, SEQ/256), 256, 0, stream>>>(q, kk, v, poO, pol);
    gemm_mlp1<<<dim3(2, NPOS/128), 512, 0, stream>>>(
        xT, poO, pol, w1b, w1f, b1f, h1, bn_sum, bn_sumsq);
    gemm_mlp2<<<dim3(2, NPOS/64), 256, 0, stream>>>(
        w2b, h1, mlp2_b, bn_sum, bn_sumsq, bn_gamma, bn_beta, out);
}

// Round 11
// 230.298 us; speedup vs baseline: 1.1138x; 1.0338x over previous
//
#include <hip/hip_runtime.h>
#include <hip/hip_bf16.h>

#define D_MODEL 256
#define HEADS 4
#define HD 64
#define BATCH 4
#define SEQ 4096
#define NPOS (BATCH*SEQ)          // 16384 positions
#define SCALE_LOG2 0.18033688011112042f  // log2(e)/8, folded into q projection
#define MCHUNKS 2                 // flash m-split (partials add; no online max)

typedef __attribute__((ext_vector_type(4))) float floatx4;
typedef __attribute__((ext_vector_type(8))) short bf16x8;
typedef __attribute__((ext_vector_type(4))) short bf16x4;
typedef __attribute__((ext_vector_type(4))) unsigned short ushortx4;

__device__ __forceinline__ float bf2f(unsigned short b) {
    return __uint_as_float(((unsigned int)b) << 16);
}
__device__ __forceinline__ unsigned short f2bf(float f) {
    unsigned int u = __float_as_uint(f);
    return (unsigned short)((u + 0x7fffu + ((u >> 16) & 1u)) >> 16);
}
__device__ __forceinline__ bf16x4 pack_bf16x4(float a, float b, float c, float d) {
    __hip_bfloat162 lo = __float22bfloat162_rn(float2{a, b});
    __hip_bfloat162 hi = __float22bfloat162_rn(float2{c, d});
    union { __hip_bfloat162 h2[2]; bf16x4 v; } u;
    u.h2[0] = lo; u.h2[1] = hi;
    return u.v;
}
__device__ __forceinline__ bf16x8 pack_bf16x8(floatx4 a, floatx4 b) {
    union { bf16x4 h[2]; bf16x8 v; } u;
    u.h[0] = pack_bf16x4(a[0], a[1], a[2], a[3]);
    u.h[1] = pack_bf16x4(b[0], b[1], b[2], b[3]);
    return u.v;
}
#define MFMA(a,b,c) __builtin_amdgcn_mfma_f32_16x16x32_bf16((a),(b),(c),0,0,0)
#define EXP2(x) __builtin_amdgcn_exp2f(x)   // native v_exp_f32 (exp2f -> ocml is ~5x slower)

// ---------------------------------------------------------------------------
// prep_all (R16 fused dispatch; R17 parallel bias-fold).
//   blocks [0,576):      linear f32->bf16 weight copies (pq,pk,pv,mlp1,mlp2)
//   blocks [576,1088):   transpose x/source -> xT/srcT [pos][256] bf16
//   blocks [1088,1104):  merge-fold GEMM  w1f[o2][c'] = sum_o W1u[o2][o]*Wmt[c'][o]
//   blocks [1104,1120):  bias fold b1f (32 o2/block, 8 threads/o2, shfl reduce)
//   block  1120:         zero bn_sum/bn_sumsq
// ---------------------------------------------------------------------------
__global__ __launch_bounds__(256) void prep_all(
        const float* __restrict__ pq_w, const float* __restrict__ pk_w,
        const float* __restrict__ pv_w, const float* __restrict__ merge_w,
        const float* __restrict__ mlp1_w, const float* __restrict__ mlp2_w,
        const float* __restrict__ mlp1_b, const float* __restrict__ merge_b,
        const float* __restrict__ x, const float* __restrict__ src,
        unsigned short* __restrict__ wqb, unsigned short* __restrict__ wkb,
        unsigned short* __restrict__ wvb,
        unsigned short* __restrict__ w1b, unsigned short* __restrict__ w2b,
        unsigned short* __restrict__ xT, unsigned short* __restrict__ srcT,
        unsigned short* __restrict__ w1f, float* __restrict__ b1f,
        float* __restrict__ bn_zero)
{
    __shared__ unsigned short smem[64 * 264];   // transpose lT / fold lA+lB union
    const int t = threadIdx.x;
    const int bx = blockIdx.x;
    if (bx < 576) {
        int linear = bx * 1024 + t * 4;
        const float* srcW; unsigned short* dst; int off;
        if (linear < 65536)       { srcW = pq_w;   dst = wqb; off = 0; }
        else if (linear < 131072) { srcW = pk_w;   dst = wkb; off = 65536; }
        else if (linear < 196608) { srcW = pv_w;   dst = wvb; off = 131072; }
        else if (linear < 458752) { srcW = mlp1_w; dst = w1b; off = 196608; }
        else                      { srcW = mlp2_w; dst = w2b; off = 458752; }
        int i = linear - off;
        float4 w = *(const float4*)&srcW[i];
        ushortx4 s = { f2bf(w.x), f2bf(w.y), f2bf(w.z), f2bf(w.w) };
        *(ushortx4*)&dst[i] = s;
        return;
    }
    if (bx < 1088) {
        unsigned short (*lT)[264] = (unsigned short (*)[264])smem;
        int z = bx - 576;
        const float* X = (z < 256) ? x : src;
        unsigned short* O = (z < 256) ? xT : srcT;
        int rem = z & 255;
        int b = rem >> 6, n0 = (rem & 63) * 64;
#pragma unroll
        for (int r = 0; r < 16; ++r) {
            int idx = r * 256 + t;
            int ch = idx >> 4, nnq = (idx & 15) * 4;
            float4 v4 = *(const float4*)&X[((size_t)b * 256 + ch) * SEQ + n0 + nnq];
            lT[nnq + 0][ch] = f2bf(v4.x);
            lT[nnq + 1][ch] = f2bf(v4.y);
            lT[nnq + 2][ch] = f2bf(v4.z);
            lT[nnq + 3][ch] = f2bf(v4.w);
        }
        __syncthreads();
#pragma unroll
        for (int r = 0; r < 8; ++r) {
            int idx = r * 256 + t;
            int row = idx >> 5, cg = (idx & 31) * 8;
            *(bf16x8*)&O[((size_t)b * SEQ + n0 + row) * 256 + cg] = *(const bf16x8*)&lT[row][cg];
        }
        return;
    }
    if (bx < 1104) {
        // merge-fold GEMM.  lB gathered from merge_w directly:
        // wmt[cp][o] = merge_w[o][((cp&63)<<2)|(cp>>6)]
        unsigned short (*lA)[40] = (unsigned short (*)[40])smem;
        unsigned short (*lB)[40] = (unsigned short (*)[40])(smem + 64 * 40);
        const int lane = t & 63, wid = t >> 6;
        const int wm = wid >> 1, wn = wid & 1;
        const int lrow = lane & 15, quad = lane >> 4;
        const int fb = bx - 1088;
        const int c0  = (fb & 1) * 128;
        const int o20 = (fb >> 1) * 64;

        floatx4 acc[2][4];
#pragma unroll
        for (int i = 0; i < 2; ++i)
#pragma unroll
            for (int j = 0; j < 4; ++j) acc[i][j] = (floatx4){0.f,0.f,0.f,0.f};

        for (int k0 = 0; k0 < 256; k0 += 32) {
#pragma unroll
            for (int r = 0; r < 2; ++r) {
                int linear = r * 1024 + t * 4;
                int row = linear >> 5, col = linear & 31;
                float4 w = *(const float4*)&mlp1_w[(size_t)(o20 + row) * 512 + 256 + k0 + col];
                ushortx4 s = { f2bf(w.x), f2bf(w.y), f2bf(w.z), f2bf(w.w) };
                *(ushortx4*)&lA[row][col] = s;
            }
#pragma unroll
            for (int r = 0; r < 2; ++r) {
                int linear = r * 256 + t;
                int row = linear >> 2, cg = (linear & 3) * 8;
                int cp = c0 + row;
                int pc = ((cp & 63) << 2) | (cp >> 6);
                unsigned short s[8];
#pragma unroll
                for (int j = 0; j < 8; ++j)
                    s[j] = f2bf(merge_w[(size_t)(k0 + cg + j) * 256 + pc]);
                *(bf16x8*)&lB[row][cg] = *(const bf16x8*)s;
            }
            __syncthreads();
            bf16x8 aF[2], bF[4];
            const int kq = quad * 8;
#pragma unroll
            for (int mt = 0; mt < 2; ++mt)
                aF[mt] = *(const bf16x8*)&lA[wm*32 + mt*16 + lrow][kq];
#pragma unroll
            for (int nt = 0; nt < 4; ++nt)
                bF[nt] = *(const bf16x8*)&lB[wn*64 + nt*16 + lrow][kq];
#pragma unroll
            for (int mt = 0; mt < 2; ++mt)
#pragma unroll
                for (int nt = 0; nt < 4; ++nt)
                    acc[mt][nt] = MFMA(aF[mt], bF[nt], acc[mt][nt]);
            __syncthreads();
        }
#pragma unroll
        for (int nt = 0; nt < 4; ++nt) {
            int cp = c0 + wn*64 + nt*16 + lrow;
#pragma unroll
            for (int mt = 0; mt < 2; ++mt)
#pragma unroll
                for (int j = 0; j < 4; ++j) {
                    int o2 = o20 + wm*32 + mt*16 + quad*4 + j;
                    w1f[(size_t)o2 * 256 + cp] = f2bf(acc[mt][nt][j]);
                }
        }
        return;
    }
    if (bx < 1120) {
        // bias fold: 32 o2 per block, 8 threads per o2, 32 k each + shfl reduce
        int o2 = (bx - 1104) * 32 + (t >> 3);
        int kl = t & 7;
        float s = 0.f;
#pragma unroll
        for (int o = 0; o < 32; ++o)
            s += mlp1_w[(size_t)o2 * 512 + 256 + kl*32 + o] * merge_b[kl*32 + o];
        s += __shfl_xor(s, 1); s += __shfl_xor(s, 2); s += __shfl_xor(s, 4);
        if (kl == 0) b1f[o2] = mlp1_b[o2] + s;
        return;
    }
    // bx == 1120: zero bn_sum/bn_sumsq (1024 floats)
    *(float4*)&bn_zero[t * 4] = float4{0.f, 0.f, 0.f, 0.f};
}

// ---------------------------------------------------------------------------
// Merged QKV projection, double-buffered LDS (1 barrier/k-step).
// grid (6, SEQ/128, B): mode = x>>1 (0=q,1=k,2=v), ob = (x&1)*128.
// v-mode epilogue staged through LDS for coalesced bf16x8 stores.
// (Deliberately left 1-deep prefetch: acc64 + 2 reg-sets would cross the
//  128-VGPR occupancy cliff — R19 note.)
// ---------------------------------------------------------------------------
__global__ __launch_bounds__(256) void proj_qkv_all(
        const unsigned short* __restrict__ Wq, const float* __restrict__ bq,
        const unsigned short* __restrict__ Wk, const float* __restrict__ bk,
        const unsigned short* __restrict__ Wv, const float* __restrict__ bv,
        const unsigned short* __restrict__ xT, const unsigned short* __restrict__ srcT,
        unsigned short* __restrict__ qo, unsigned short* __restrict__ ko,
        unsigned short* __restrict__ vo)
{
    __shared__ unsigned short smem[2][128 * 80];   // per buf: lA 128x40, lB 128x40
    unsigned short (*stage)[72] = (unsigned short (*)[72])&smem[0][0];
    unsigned short* stage2 = &smem[0][0];          // v-mode: flat [64][132] u16
    const int t = threadIdx.x;
    const int lane = t & 63, wid = t >> 6;
    const int wm = wid >> 1, wn = wid & 1;
    const int lrow = lane & 15, quad = lane >> 4;
    const int mode = blockIdx.x >> 1;
    const int ob = (blockIdx.x & 1) * 128;
    const int n0 = blockIdx.y * 128;
    const int b  = blockIdx.z;
    const unsigned short* W  = (mode == 0) ? Wq : (mode == 1) ? Wk : Wv;
    const float* bias        = (mode == 0) ? bq : (mode == 1) ? bk : bv;
    const unsigned short* XT = (mode == 0) ? xT : srcT;
    unsigned short* out      = (mode == 0) ? qo : (mode == 1) ? ko : vo;

    const int srow[2] = { (0*256 + t) >> 2, (1*256 + t) >> 2 };
    const int scg = (t & 3) * 8;

    floatx4 acc[4][4];
#pragma unroll
    for (int i = 0; i < 4; ++i)
#pragma unroll
        for (int j = 0; j < 4; ++j) acc[i][j] = (floatx4){0.f,0.f,0.f,0.f};

    bf16x8 rW[2], rX[2];
#pragma unroll
    for (int r = 0; r < 2; ++r) {
        rW[r] = *(const bf16x8*)&W[(size_t)(ob + srow[r]) * 256 + scg];
        rX[r] = *(const bf16x8*)&XT[((size_t)b * SEQ + n0 + srow[r]) * 256 + scg];
    }
#pragma unroll
    for (int r = 0; r < 2; ++r) {
        *(bf16x8*)&smem[0][srow[r]*40 + scg]           = rW[r];
        *(bf16x8*)&smem[0][128*40 + srow[r]*40 + scg]  = rX[r];
    }
    __syncthreads();

    int p = 0;
    for (int kc = 0; kc < 8; ++kc) {
        const bool pre = (kc + 1 < 8);
        if (pre) {
            const int k1 = (kc + 1) * 32;
#pragma unroll
            for (int r = 0; r < 2; ++r) {
                rW[r] = *(const bf16x8*)&W[(size_t)(ob + srow[r]) * 256 + k1 + scg];
                rX[r] = *(const bf16x8*)&XT[((size_t)b * SEQ + n0 + srow[r]) * 256 + k1 + scg];
            }
        }
        bf16x8 aF[4], bF[4];
        const int kq = quad * 8;
#pragma unroll
        for (int mt = 0; mt < 4; ++mt)
            aF[mt] = *(const bf16x8*)&smem[p][(wm*64 + mt*16 + lrow)*40 + kq];
#pragma unroll
        for (int nt = 0; nt < 4; ++nt)
            bF[nt] = *(const bf16x8*)&smem[p][128*40 + (wn*64 + nt*16 + lrow)*40 + kq];
#pragma unroll
        for (int mt = 0; mt < 4; ++mt)
#pragma unroll
            for (int nt = 0; nt < 4; ++nt)
                acc[mt][nt] = MFMA(aF[mt], bF[nt], acc[mt][nt]);
        if (pre) {
#pragma unroll
            for (int r = 0; r < 2; ++r) {
                *(bf16x8*)&smem[p^1][srow[r]*40 + scg]          = rW[r];
                *(bf16x8*)&smem[p^1][128*40 + srow[r]*40 + scg] = rX[r];
            }
        }
        __syncthreads();
        p ^= 1;
    }
    const float osc = (mode == 0) ? SCALE_LOG2 : 1.0f;
    if (mode == 2) {
        // v layout: [bh][d][m].  Stage [64 o][128 n] halves in LDS, then write
        // bf16x8 rows (16 lanes cover 256 contiguous bytes of n).
        for (int half = 0; half < 2; ++half) {
            __syncthreads();
            if (wm == half) {
#pragma unroll
                for (int mt = 0; mt < 4; ++mt)
#pragma unroll
                    for (int j = 0; j < 4; ++j) {
                        int ol = mt*16 + quad*4 + j;         // 0..63
                        float bvv = bias[ob + half*64 + ol];
#pragma unroll
                        for (int nt = 0; nt < 4; ++nt) {
                            int n = wn*64 + nt*16 + lrow;    // 0..127
                            stage2[ol*132 + n] = f2bf(acc[mt][nt][j] + bvv);
                        }
                    }
            }
            __syncthreads();
#pragma unroll
            for (int i = 0; i < 4; ++i) {
                int c = i * 256 + t;                         // 0..1023
                int row = c >> 4, sub = c & 15;              // row 0..63, sub 0..15
                int o = ob + half*64 + row;
                int d = o >> 2, h = o & 3;
                *(bf16x8*)&out[((size_t)(b*HEADS + h) * HD + d) * SEQ + n0 + sub*8] =
                    *(const bf16x8*)&stage2[row*132 + sub*8];
            }
        }
        return;
    }
    for (int half = 0; half < 2; ++half) {
        __syncthreads();
        if (wm == half) {
#pragma unroll
            for (int mt = 0; mt < 4; ++mt)
#pragma unroll
                for (int j = 0; j < 4; ++j) {
                    int o = ob + half*64 + mt*16 + quad*4 + j;
                    float bvv = bias[o];
                    int col = j*16 + mt*4 + quad;
#pragma unroll
                    for (int nt = 0; nt < 4; ++nt) {
                        int n = wn*64 + nt*16 + lrow;
                        stage[n][col] = f2bf((acc[mt][nt][j] + bvv) * osc);
                    }
                }
        }
        __syncthreads();
#pragma unroll
        for (int i = 0; i < 4; ++i) {
            int c = i * 256 + t;
            int n = c >> 3, h = (c >> 1) & 3, sub = c & 1;
            bf16x8 val = *(const bf16x8*)&stage[n][h*16 + sub*8];
            int d0 = (ob >> 2) + half*16 + sub*8;
            *(bf16x8*)&out[((size_t)(b*HEADS + h) * SEQ + n0 + n) * HD + d0] = val;
        }
    }
}

// ---------------------------------------------------------------------------
// Flash attention, transposed-softmax, m-split, double-buffered LDS.
// grid (16*MCHUNKS, SEQ/256) = (32, 16): 512 blocks, 2/CU.
// R14 (verified R6-R10: ~71.5us, MfmaUtil 45-46%): structure frozen.
// R18 (kept): interleaved poO[hb][n][chunk][64] / pol[hb][n][chunk].
// ---------------------------------------------------------------------------
__global__ __launch_bounds__(256, 2) void flash_attn(
        const unsigned short* __restrict__ q,
        const unsigned short* __restrict__ k,
        const unsigned short* __restrict__ v,
        unsigned short* __restrict__ poO, float* __restrict__ pol)
{
    __shared__ unsigned short smem[2][9216];   // per buf: lK 64x72 then lV 64x72
    const int t = threadIdx.x, lane = t & 63, wid = t >> 6;
    const int lrow = lane & 15, quad = lane >> 4;
    const int bc = blockIdx.x, qt = blockIdx.y;
    const int bh = bc & 15, chunk = bc >> 4;
    const int hb = (bh & 3) * BATCH + (bh >> 2);
    const int r0 = qt * 256 + wid * 64;

    bf16x8 qf[4][2];
#pragma unroll
    for (int nh = 0; nh < 4; ++nh) {
        const size_t base = ((size_t)bh * SEQ + r0 + nh*16 + lrow) * HD;
        qf[nh][0] = *(const bf16x8*)&q[base + quad * 8];
        qf[nh][1] = *(const bf16x8*)&q[base + 32 + quad * 8];
    }
    bf16x8 ones;
#pragma unroll
    for (int i = 0; i < 8; ++i) ones[i] = (short)0x3F80;  // bf16 1.0
    int mmv[2], cgv[2], krv[2];
#pragma unroll
    for (int r = 0; r < 2; ++r) {
        int linear = r * 256 + t;
        int mm = linear >> 3, cg = (linear & 7) * 8;
        int c2 = mm >> 5, mp = mm & 31;
        mmv[r] = mm; cgv[r] = cg;
        krv[r] = (c2 << 5) + ((mp & 4) << 2) + ((mp >> 3) << 2) + (mp & 3);
    }
    const size_t kbase = ((size_t)bh * SEQ + chunk * (SEQ/MCHUNKS));
    const size_t vbase = (size_t)bh * HD;
    const int moff = chunk * (SEQ/MCHUNKS);
    const int NIT = SEQ / MCHUNKS / 64;

    floatx4 oacc[4][4], oaccL[4];
#pragma unroll
    for (int nh = 0; nh < 4; ++nh) {
        oaccL[nh] = (floatx4){0.f,0.f,0.f,0.f};
#pragma unroll
        for (int i = 0; i < 4; ++i) oacc[nh][i] = (floatx4){0.f,0.f,0.f,0.f};
    }

    {
        bf16x8 pk[2], pv[2];
#pragma unroll
        for (int r = 0; r < 2; ++r) {
            pk[r] = *(const bf16x8*)&k[(kbase + mmv[r]) * HD + cgv[r]];
            pv[r] = *(const bf16x8*)&v[(vbase + mmv[r]) * SEQ + moff + cgv[r]];
        }
#pragma unroll
        for (int r = 0; r < 2; ++r) {
            *(bf16x8*)&smem[0][krv[r]*72 + cgv[r]]        = pk[r];
            *(bf16x8*)&smem[0][4608 + mmv[r]*72 + cgv[r]] = pv[r];
        }
    }
    __syncthreads();

    int p = 0;
#pragma unroll 1
    for (int it = 0; it < NIT; ++it) {
        bf16x8 pk[2], pv[2];
        const bool pre = (it + 1 < NIT);
        if (pre) {
            const int m1 = (it + 1) * 64;
#pragma unroll
            for (int r = 0; r < 2; ++r) {
                pk[r] = *(const bf16x8*)&k[(kbase + m1 + mmv[r]) * HD + cgv[r]];
                pv[r] = *(const bf16x8*)&v[(vbase + mmv[r]) * SEQ + moff + m1 + cgv[r]];
            }
        }
        const unsigned short* lS = smem[p];

#pragma unroll
        for (int c2 = 0; c2 < 2; ++c2) {
            floatx4 sa[2][4];
#pragma unroll
            for (int AB = 0; AB < 2; ++AB)
#pragma unroll
                for (int nh = 0; nh < 4; ++nh)
                    sa[AB][nh] = (floatx4){0.f,0.f,0.f,0.f};
            __builtin_amdgcn_s_setprio(1);
#pragma unroll
            for (int AB = 0; AB < 2; ++AB) {
#pragma unroll
                for (int kc = 0; kc < 2; ++kc) {
                    bf16x8 kf = *(const bf16x8*)&lS[(c2*32 + AB*16 + lrow)*72 + kc*32 + quad*8];
#pragma unroll
                    for (int nh = 0; nh < 4; ++nh)
                        sa[AB][nh] = MFMA(kf, qf[nh][kc], sa[AB][nh]);
                }
            }
            __builtin_amdgcn_s_setprio(0);
            bf16x8 pf8[4];
#pragma unroll
            for (int nh = 0; nh < 4; ++nh) {
                floatx4 ea, eb;
#pragma unroll
                for (int i = 0; i < 4; ++i) { ea[i] = EXP2(sa[0][nh][i]); eb[i] = EXP2(sa[1][nh][i]); }
                pf8[nh] = pack_bf16x8(ea, eb);
            }
            __builtin_amdgcn_s_setprio(1);
#pragma unroll
            for (int nh = 0; nh < 4; ++nh)
                oaccL[nh] = MFMA(ones, pf8[nh], oaccL[nh]);
#pragma unroll
            for (int dt = 0; dt < 4; ++dt) {
                bf16x8 vf = *(const bf16x8*)&lS[4608 + (dt*16 + lrow)*72 + c2*32 + quad*8];
#pragma unroll
                for (int nh = 0; nh < 4; ++nh)
                    oacc[nh][dt] = MFMA(vf, pf8[nh], oacc[nh][dt]);
            }
            __builtin_amdgcn_s_setprio(0);
        }
        if (pre) {
#pragma unroll
            for (int r = 0; r < 2; ++r) {
                *(bf16x8*)&smem[p^1][krv[r]*72 + cgv[r]]        = pk[r];
                *(bf16x8*)&smem[p^1][4608 + mmv[r]*72 + cgv[r]] = pv[r];
            }
        }
        __syncthreads();
        p ^= 1;
    }
    const size_t nb = (size_t)hb * SEQ + qt * 256;   // row base (interleaved layout)
    if (lane < 16) {
#pragma unroll
        for (int nh = 0; nh < 4; ++nh)
            pol[(nb + wid*64 + nh*16 + lrow) * MCHUNKS + chunk] = oaccL[nh][0];
    }
    // epilogue: packed b64 stores, [256][72] staging (uses both LDS buffers)
    unsigned short* stB = (unsigned short*)&smem[0][0];
#pragma unroll
    for (int nh = 0; nh < 4; ++nh)
#pragma unroll
        for (int dt = 0; dt < 4; ++dt) {
            bf16x4 pv4 = pack_bf16x4(oacc[nh][dt][0], oacc[nh][dt][1],
                                     oacc[nh][dt][2], oacc[nh][dt][3]);
            *(bf16x4*)&stB[(wid*64 + nh*16 + lrow)*72 + dt*16 + quad*4] = pv4;
        }
    __syncthreads();
#pragma unroll
    for (int i = 0; i < 8; ++i) {
        int c = i * 256 + t;
        int row = c >> 3, sub = c & 7;
        *(bf16x8*)&poO[((nb + row) * MCHUNKS + chunk) * HD + sub*8] =
            *(const bf16x8*)&stB[row*72 + sub*8];
    }
}

// ---------------------------------------------------------------------------
// mlp1 (R19: 2-DEEP register prefetch).  At 1 block/CU the 1-deep pipeline
// stalls every barrier on loads issued one k-step earlier (~80-160 MFMA
// cycles to hide ~300-900cy latency) — R9/R10 traffic cuts were null, so the
// sink is latency.  Two reg sets, pair-unrolled loop: tile k+2's loads issue
// while tile k computes; LDS stays 2 buffers (alternate 0/1 per pair).  The
// poO combine moved to store-site so its waitcnt lands 2 phases after issue.
// grid (2, NPOS/128), 512 threads, per-wave 64x64 out (16 MFMA : 8 reads).
// ---------------------------------------------------------------------------
__global__ __launch_bounds__(512) void gemm_mlp1(
        const unsigned short* __restrict__ xT, const unsigned short* __restrict__ poO,
        const float* __restrict__ pol,
        const unsigned short* __restrict__ w1b, const unsigned short* __restrict__ w1f,
        const float* __restrict__ b1f, unsigned short* __restrict__ h1,
        float* __restrict__ sums, float* __restrict__ sumsq)
{
    __shared__ unsigned short lA[2][128][40];
    __shared__ unsigned short lB[2][256][40];
    __shared__ float sInv[512];
    __shared__ float sRed[4][4][16][2];
    const int t = threadIdx.x;
    const int lane = t & 63, wid = t >> 6;
    const int wp = wid >> 2, wo = wid & 3;
    const int lrow = lane & 15, quad = lane >> 4;
    const int o0 = blockIdx.x * 256;
    const int p0 = blockIdx.y * 128;
    const int b = p0 >> 12, n0 = p0 & (SEQ - 1);

    {
        int h = t >> 7, nn = t & 127;          // 4 heads x 128 local pos
        int hb = h * BATCH + b;
        float2 l2 = *(const float2*)&pol[((size_t)hb * SEQ + n0 + nn) * MCHUNKS];
        sInv[t] = 1.0f / (l2.x + l2.y);
    }
    __syncthreads();

    const int arow = t >> 2, acg = (t & 3) * 8;              // 0..127
    const int brow[2] = { (0*512 + t) >> 2, (1*512 + t) >> 2 };  // 0..255

    floatx4 acc[4][4];
#pragma unroll
    for (int i = 0; i < 4; ++i)
#pragma unroll
        for (int j = 0; j < 4; ++j) acc[i][j] = (floatx4){0.f,0.f,0.f,0.f};

    auto loadT = [&](int k0, bf16x8& ra, bf16x8& rb, bf16x8 (&rBv)[2]) {
        if (k0 < 256) {
            ra = *(const bf16x8*)&xT[(size_t)(p0 + arow) * 256 + k0 + acg];
#pragma unroll
            for (int r = 0; r < 2; ++r)
                rBv[r] = *(const bf16x8*)&w1b[(size_t)(o0 + brow[r]) * 512 + k0 + acg];
        } else {
            const int kk2 = k0 - 256;
            const int h = kk2 >> 6, d0 = kk2 & 63, hb = h * BATCH + b;
            const unsigned short* bse =
                &poO[(((size_t)hb * SEQ + n0 + arow) * MCHUNKS) * HD + d0 + acg];
            ra = *(const bf16x8*)bse;
            rb = *(const bf16x8*)(bse + HD);                 // chunk 1: +128B
#pragma unroll
            for (int r = 0; r < 2; ++r)
                rBv[r] = *(const bf16x8*)&w1f[(size_t)(o0 + brow[r]) * 256 + kk2 + acg];
        }
    };
    auto storeT = [&](int buf, int k0, bf16x8& ra, bf16x8& rb, bf16x8 (&rBv)[2]) {
        bf16x8 av;
        if (k0 < 256) {
            av = ra;
        } else {
            const int kk2 = k0 - 256;
            const int h = kk2 >> 6;
            float inv = sInv[h*128 + arow];
            unsigned short res[8];
#pragma unroll
            for (int i = 0; i < 8; ++i)
                res[i] = f2bf((bf2f((unsigned short)ra[i]) + bf2f((unsigned short)rb[i])) * inv);
            av = *(const bf16x8*)res;
        }
        *(bf16x8*)&lA[buf][arow][acg] = av;
#pragma unroll
        for (int r = 0; r < 2; ++r) *(bf16x8*)&lB[buf][brow[r]][acg] = rBv[r];
    };
    auto computeT = [&](int buf) {
        bf16x8 aF[4], bF[4];
        const int kq = quad * 8;
#pragma unroll
        for (int mt = 0; mt < 4; ++mt)
            aF[mt] = *(const bf16x8*)&lA[buf][wp*64 + mt*16 + lrow][kq];
#pragma unroll
        for (int nt = 0; nt < 4; ++nt)
            bF[nt] = *(const bf16x8*)&lB[buf][wo*64 + nt*16 + lrow][kq];
#pragma unroll
        for (int mt = 0; mt < 4; ++mt)
#pragma unroll
            for (int nt = 0; nt < 4; ++nt)
                acc[mt][nt] = MFMA(aF[mt], bF[nt], acc[mt][nt]);
    };

    bf16x8 rAa0, rAb0, rB0[2];
    bf16x8 rAa1, rAb1, rB1[2];

    loadT(0, rAa0, rAb0, rB0);
    storeT(0, 0, rAa0, rAb0, rB0);
    loadT(32, rAa0, rAb0, rB0);        // set0 <- tile 1
    __syncthreads();

#pragma unroll
    for (int kc = 0; kc < 16; kc += 2) {
        // LDS[0] = tile kc; set0 = tile kc+1 (in flight >= 1 phase)
        if (kc + 2 < 16) loadT((kc + 2) * 32, rAa1, rAb1, rB1);
        computeT(0);
        storeT(1, (kc + 1) * 32, rAa0, rAb0, rB0);
        __syncthreads();
        // LDS[1] = tile kc+1; set1 = tile kc+2 (in flight >= 1 phase)
        if (kc + 3 < 16) loadT((kc + 3) * 32, rAa0, rAb0, rB0);
        computeT(1);
        if (kc + 2 < 16) storeT(0, (kc + 2) * 32, rAa1, rAb1, rB1);
        __syncthreads();
    }
#pragma unroll
    for (int nt = 0; nt < 4; ++nt) {
        int o = o0 + wo*64 + nt*16 + lrow;
        float bvv = b1f[o];
        float s = 0.f, qs = 0.f;
#pragma unroll
        for (int mt = 0; mt < 4; ++mt)
#pragma unroll
            for (int j = 0; j < 4; ++j) {
                int pos = p0 + wp*64 + mt*16 + quad*4 + j;
                float val = acc[mt][nt][j] + bvv;
                h1[(size_t)pos * 512 + o] = f2bf(val);
                s += val; qs += val * val;
            }
        s  += __shfl_xor(s, 16);  s  += __shfl_xor(s, 32);
        qs += __shfl_xor(qs, 16); qs += __shfl_xor(qs, 32);
        if (wp == 1 && lane < 16) {
            sRed[wo][nt][lrow][0] = s;
            sRed[wo][nt][lrow][1] = qs;
        }
        __syncthreads();
        if (wp == 0 && lane < 16) {
            atomicAdd(&sums[o],  s  + sRed[wo][nt][lrow][0]);
            atomicAdd(&sumsq[o], qs + sRed[wo][nt][lrow][1]);
        }
    }
}

// ---------------------------------------------------------------------------
// mlp2 (R19: 2-DEEP register prefetch, same rationale as mlp1; BN+ReLU
// transform moved to store-site so the load waitcnt lands 2 phases after
// issue).  out[b][o][n] f32 = W2 @ relu(bn(h1))^T + bias. grid (2, NPOS/64).
// ---------------------------------------------------------------------------
__global__ __launch_bounds__(256) void gemm_mlp2(
        const unsigned short* __restrict__ W2, const unsigned short* __restrict__ h1,
        const float* __restrict__ bias,
        const float* __restrict__ sums, const float* __restrict__ sumsq,
        const float* __restrict__ gamma, const float* __restrict__ beta,
        float* __restrict__ out)
{
    __shared__ unsigned short lA[2][128][40];
    __shared__ unsigned short lB[2][64][40];
    __shared__ float sSc[512], sSh[512];
    const int t = threadIdx.x;
    const int lane = t & 63, wid = t >> 6;
    const int wm = wid >> 1, wn = wid & 1;
    const int lrow = lane & 15, quad = lane >> 4;
    const int o0 = blockIdx.x * 128;
    const int p0 = blockIdx.y * 64;

#pragma unroll
    for (int cc = 0; cc < 2; ++cc) {
        int c = cc * 256 + t;
        float mean = sums[c] * (1.0f / NPOS);
        float var  = sumsq[c] * (1.0f / NPOS) - mean * mean;
        float sc = gamma[c] * rsqrtf(var + 1e-5f);
        sSc[c] = sc;
        sSh[c] = beta[c] - mean * sc;
    }
    __syncthreads();

    const int arow[2] = { (0*256 + t) >> 2, (1*256 + t) >> 2 };
    const int acg = (t & 3) * 8;
    const int brow = t >> 2;

    floatx4 acc[4][2];
#pragma unroll
    for (int i = 0; i < 4; ++i)
#pragma unroll
        for (int j = 0; j < 2; ++j) acc[i][j] = (floatx4){0.f,0.f,0.f,0.f};

    auto loadT = [&](int k0, bf16x8 (&rw)[2], bf16x8& rh) {
#pragma unroll
        for (int r = 0; r < 2; ++r)
            rw[r] = *(const bf16x8*)&W2[(size_t)(o0 + arow[r]) * 512 + k0 + acg];
        rh = *(const bf16x8*)&h1[(size_t)(p0 + brow) * 512 + k0 + acg];
    };
    auto storeT = [&](int buf, int k0, bf16x8 (&rw)[2], bf16x8& rh) {
#pragma unroll
        for (int r = 0; r < 2; ++r) *(bf16x8*)&lA[buf][arow[r]][acg] = rw[r];
        unsigned short res[8];
#pragma unroll
        for (int i = 0; i < 8; ++i) {
            int c = k0 + acg + i;
            float f = bf2f((unsigned short)rh[i]);
            f = fmaxf(f * sSc[c] + sSh[c], 0.f);
            res[i] = f2bf(f);
        }
        *(bf16x8*)&lB[buf][brow][acg] = *(const bf16x8*)res;
    };
    auto computeT = [&](int buf) {
        bf16x8 aF[4], bF[2];
        const int kq = quad * 8;
#pragma unroll
        for (int mt = 0; mt < 4; ++mt)
            aF[mt] = *(const bf16x8*)&lA[buf][wm*64 + mt*16 + lrow][kq];
#pragma unroll
        for (int nt = 0; nt < 2; ++nt)
            bF[nt] = *(const bf16x8*)&lB[buf][wn*32 + nt*16 + lrow][kq];
#pragma unroll
        for (int mt = 0; mt < 4; ++mt)
#pragma unroll
            for (int nt = 0; nt < 2; ++nt)
                acc[mt][nt] = MFMA(aF[mt], bF[nt], acc[mt][nt]);
    };

    bf16x8 rW0[2], rH0, rW1[2], rH1;

    loadT(0, rW0, rH0);
    storeT(0, 0, rW0, rH0);
    loadT(32, rW0, rH0);               // set0 <- tile 1
    __syncthreads();

#pragma unroll
    for (int kc = 0; kc < 16; kc += 2) {
        if (kc + 2 < 16) loadT((kc + 2) * 32, rW1, rH1);
        computeT(0);
        storeT(1, (kc + 1) * 32, rW0, rH0);
        __syncthreads();
        if (kc + 3 < 16) loadT((kc + 3) * 32, rW0, rH0);
        computeT(1);
        if (kc + 2 < 16) storeT(0, (kc + 2) * 32, rW1, rH1);
        __syncthreads();
    }
#pragma unroll
    for (int mt = 0; mt < 4; ++mt)
#pragma unroll
        for (int j = 0; j < 4; ++j) {
            int o = o0 + wm*64 + mt*16 + quad*4 + j;
            float bvv = bias[o];
#pragma unroll
            for (int nt = 0; nt < 2; ++nt) {
                int pos = p0 + wn*32 + nt*16 + lrow;
                int b = pos >> 12, n = pos & (SEQ - 1);
                out[((size_t)b * D_MODEL + o) * SEQ + n] = acc[mt][nt][j] + bvv;
            }
        }
}

// ---------------------------------------------------------------------------
extern "C" void kernel_launch(void* const* d_in, const int* in_sizes, int n_in,
                              void* d_out, int out_size, void* d_ws, size_t ws_size,
                              hipStream_t stream)
{
    (void)in_sizes; (void)n_in; (void)out_size; (void)ws_size;
    const float* x        = (const float*)d_in[0];
    const float* source   = (const float*)d_in[1];
    const float* pq_w     = (const float*)d_in[2];
    const float* pq_b     = (const float*)d_in[3];
    const float* pk_w     = (const float*)d_in[4];
    const float* pk_b     = (const float*)d_in[5];
    const float* pv_w     = (const float*)d_in[6];
    const float* pv_b     = (const float*)d_in[7];
    const float* merge_w  = (const float*)d_in[8];
    const float* merge_b  = (const float*)d_in[9];
    const float* mlp1_w   = (const float*)d_in[10];
    const float* mlp1_b   = (const float*)d_in[11];
    const float* bn_gamma = (const float*)d_in[12];
    const float* bn_beta  = (const float*)d_in[13];
    const float* mlp2_w   = (const float*)d_in[14];
    const float* mlp2_b   = (const float*)d_in[15];
    float* out = (float*)d_out;

    char* ws = (char*)d_ws;
    const size_t MB = 1ull << 20;
    unsigned short* xT   = (unsigned short*)(ws);             //  8 MB [pos][256]
    unsigned short* srcT = (unsigned short*)(ws + 8*MB);      //  8 MB [pos][256]
    unsigned short* q    = (unsigned short*)(ws + 16*MB);     //  8 MB [bh][n][64]
    unsigned short* kk   = (unsigned short*)(ws + 24*MB);     //  8 MB [bh][m][64]
    unsigned short* v    = (unsigned short*)(ws + 32*MB);     //  8 MB [bh][64][m]
    unsigned short* poO  = (unsigned short*)(ws + 40*MB);     // 16 MB bf16 partial O [hb][n][chunk][64]
    unsigned short* h1   = (unsigned short*)(ws + 16*MB);     // 16 MB [pos][512] — aliases q+kk (dead post-flash)
    float* pol = (float*)(ws + 72*MB);                        // 512 KB partial l [hb][n][chunk]
    unsigned short* wqb = (unsigned short*)(ws + 73*MB);
    unsigned short* wkb = wqb + 65536;
    unsigned short* wvb = wkb + 65536;
    unsigned short* w1b = wvb + 65536;                        // 512 KB full mlp1_w
    unsigned short* w2b = w1b + 262144;                       // 256 KB
    unsigned short* w1f = w2b + 131072;                       // 256 KB folded
    float* b1f = (float*)(w1f + 131072);                      // 512 folded bias
    float* bn_sum = b1f + 512;
    float* bn_sumsq = bn_sum + 512;

    prep_all<<<dim3(1121), 256, 0, stream>>>(
        pq_w, pk_w, pv_w, merge_w, mlp1_w, mlp2_w, mlp1_b, merge_b, x, source,
        wqb, wkb, wvb, w1b, w2b, xT, srcT, w1f, b1f, bn_sum);
    proj_qkv_all<<<dim3(6, SEQ/128, BATCH), 256, 0, stream>>>(
        wqb, pq_b, wkb, pk_b, wvb, pv_b, xT, srcT, q, kk, v);
    flash_attn<<<dim3(16*MCHUNKS, SEQ/256), 256, 0, stream>>>(q, kk, v, poO, pol);
    gemm_mlp1<<<dim3(2, NPOS/128), 512, 0, stream>>>(
        xT, poO, pol, w1b, w1f, b1f, h1, bn_sum, bn_sumsq);
    gemm_mlp2<<<dim3(2, NPOS/64), 256, 0, stream>>>(
        w2b, h1, mlp2_b, bn_sum, bn_sumsq, bn_gamma, bn_beta, out);
}